// Round 8
// baseline (17508.678 us; speedup 1.0000x reference)
//
#include <hip/hip_runtime.h>
#include <cmath>

namespace {

constexpr int B_ = 8, L_ = 128, IN_ = 64, H_ = 800, C_ = 800, A_ = 128, HD_ = 8;
constexpr int F_ = 870;
constexpr int KX_ = IN_ + C_;          // 864
constexpr int KO_ = HD_ * F_;          // 6960
constexpr double RAD_ = 8.0, BOND_ = 3.8;
constexpr int NT = 512;

// ---- float region of ws ----
constexpr size_t OF_RES = 16;                                   // res [B][L][H] f32
constexpr size_t OF_WIT = OF_RES + (size_t)B_ * L_ * H_;        // W_ih^T [2400][864]
constexpr size_t OF_WHT = OF_WIT + (size_t)3 * H_ * KX_;        // W_hh^T [2400][800]
constexpr size_t OF_WOT = OF_WHT + (size_t)3 * H_ * H_;         // Wout^T [800][6960]
constexpr size_t FLT_END = OF_WOT + (size_t)C_ * KO_;           // even
// ---- double region ----
constexpr size_t D_ST  = 0;                                     // state dbuf [2][B][H]
constexpr size_t D_CTX = D_ST + 2ull * B_ * H_;                 // context [B][C]
constexpr size_t D_ANG = D_CTX + (size_t)B_ * C_;               // angles [B][L][3]
constexpr size_t D_POS = D_ANG + (size_t)B_ * L_ * 3;           // positions [B][L][3][3]
constexpr size_t D_DST = D_POS + (size_t)B_ * L_ * 9;           // dist [2][B][L][3] parity
constexpr size_t D_G   = D_DST + 2ull * B_ * L_ * 3;            // G [B][L][A]
constexpr size_t D_W   = D_G + (size_t)B_ * L_ * A_;            // w [B][L][HD]
constexpr size_t D_PN  = D_W + (size_t)B_ * L_ * HD_;           // pooledN [B][KO]
constexpr size_t D_END = D_PN + (size_t)B_ * KO_;
constexpr size_t WS_BYTES = FLT_END * 4 + D_END * 8;            // ~43.5 MB

__device__ void transp(const float* __restrict__ src, float* __restrict__ dst,
                       int R, int Cn, float* sm) {
  const int tr_ = (R + 31) >> 5, tc_ = (Cn + 31) >> 5;
  for (int t = blockIdx.x; t < tr_ * tc_; t += gridDim.x) {
    const int r0 = (t / tc_) << 5, c0 = (t % tc_) << 5;
    __syncthreads();
    for (int e = threadIdx.x; e < 1024; e += NT) {
      const int rr = e >> 5, cc = e & 31, r = r0 + rr, c = c0 + cc;
      sm[rr * 33 + cc] = (r < R && c < Cn) ? src[(size_t)r * Cn + c] : 0.0f;
    }
    __syncthreads();
    for (int e = threadIdx.x; e < 1024; e += NT) {
      const int cc = e >> 5, rr = e & 31, r = r0 + rr, c = c0 + cc;
      if (r < R && c < Cn) dst[(size_t)c * R + r] = sm[rr * 33 + cc];
    }
  }
}

} // namespace

// ============ init: zero state+ctx, G pre-init, weight transposes ============
__global__ __launch_bounds__(NT)
void srnn_init(const float* __restrict__ data, const float* __restrict__ W_ih,
               const float* __restrict__ W_hh, const float* __restrict__ W1,
               const float* __restrict__ b1, const float* __restrict__ Wout,
               float* __restrict__ ws)
{
  __shared__ float smf[1056];
  float* WihT  = ws + OF_WIT;
  float* WhhT  = ws + OF_WHT;
  float* WoutT = ws + OF_WOT;
  double* wd   = (double*)(ws + FLT_END);
  double* Gd   = wd + D_G;
  const int bid = blockIdx.x, tid = threadIdx.x;

  for (int i = bid * NT + tid; i < (int)(D_ANG - D_ST); i += 256 * NT)
    wd[i] = 0.0;                                 // st dbuf + ctx = 0 (every call)
  {
    const int i = bid * NT + tid;                // B*L*A == 256*512
    const int a = i & (A_ - 1);
    const int bj = i >> 7;
    double acc = (double)b1[a];
    const float* dr = data + (size_t)bj * IN_;
    #pragma unroll 8
    for (int k = 0; k < IN_; ++k)
      acc = fma((double)dr[k], (double)W1[(size_t)(H_ + k) * A_ + a], acc);
    Gd[i] = acc;
  }
  transp(W_ih, WihT, KX_, 3 * H_, smf);
  transp(W_hh, WhhT, H_, 3 * H_, smf);
  transp(Wout, WoutT, KO_, C_, smf);
}

// ============ KA: GRU (blocks 0..99) || e/logits/w (blocks 100..227) ============
__global__ __launch_bounds__(NT)
void srnn_a(const float* __restrict__ data, const float* __restrict__ b_ih,
            const float* __restrict__ b_hh, const float* __restrict__ W1,
            const float* __restrict__ W2, float* __restrict__ ws, int idx)
{
  float* res   = ws + OF_RES;
  const float* WihT = ws + OF_WIT;
  const float* WhhT = ws + OF_WHT;
  double* wd   = (double*)(ws + FLT_END);
  double* st2  = wd + D_ST;
  double* ctxD = wd + D_CTX;
  double* angD = wd + D_ANG;
  double* dstD = wd + D_DST;
  double* Gd   = wd + D_G;
  double* wAr  = wd + D_W;

  const int bid = blockIdx.x, tid = threadIdx.x;
  const int wid = tid >> 6, lane = tid & 63;
  const int rp = idx & 1;
  const double* sOld = st2 + (size_t)rp * B_ * H_;
  double* sNew = st2 + (size_t)(rp ^ 1) * B_ * H_;
  const double* dstR = dstD + (size_t)(idx & 1) * (B_ * L_ * 3);

  if (bid < 100) {
    const int i = bid * 8 + wid;                 // neuron, one wave each
    const int b = lane >> 3, ks = lane & 7;
    const float4* wr4 = reinterpret_cast<const float4*>(WihT + (size_t)i * KX_);
    const float4* wz4 = reinterpret_cast<const float4*>(WihT + (size_t)(H_ + i) * KX_);
    const float4* wn4 = reinterpret_cast<const float4*>(WihT + (size_t)(2 * H_ + i) * KX_);
    const float4* dx4 = reinterpret_cast<const float4*>(data + ((size_t)b * L_ + idx) * IN_);
    const double* cx = ctxD + (size_t)b * C_;
    double axr = 0., axz = 0., axn = 0.;
    #pragma unroll
    for (int j = 0; j < 2; ++j) {
      const int q = ks + 8 * j;
      const float4 x4 = dx4[q];
      const float4 r4 = wr4[q], z4 = wz4[q], n4 = wn4[q];
      const double x0 = x4.x, x1 = x4.y, x2 = x4.z, x3 = x4.w;
      axr = fma((double)r4.x, x0, axr); axr = fma((double)r4.y, x1, axr);
      axr = fma((double)r4.z, x2, axr); axr = fma((double)r4.w, x3, axr);
      axz = fma((double)z4.x, x0, axz); axz = fma((double)z4.y, x1, axz);
      axz = fma((double)z4.z, x2, axz); axz = fma((double)z4.w, x3, axz);
      axn = fma((double)n4.x, x0, axn); axn = fma((double)n4.y, x1, axn);
      axn = fma((double)n4.z, x2, axn); axn = fma((double)n4.w, x3, axn);
    }
    for (int j = 2; j < 27; ++j) {
      const int q = ks + 8 * j;
      const int e = 4 * q - 64;
      const double x0 = cx[e], x1 = cx[e + 1], x2 = cx[e + 2], x3 = cx[e + 3];
      const float4 r4 = wr4[q], z4 = wz4[q], n4 = wn4[q];
      axr = fma((double)r4.x, x0, axr); axr = fma((double)r4.y, x1, axr);
      axr = fma((double)r4.z, x2, axr); axr = fma((double)r4.w, x3, axr);
      axz = fma((double)z4.x, x0, axz); axz = fma((double)z4.y, x1, axz);
      axz = fma((double)z4.z, x2, axz); axz = fma((double)z4.w, x3, axz);
      axn = fma((double)n4.x, x0, axn); axn = fma((double)n4.y, x1, axn);
      axn = fma((double)n4.z, x2, axn); axn = fma((double)n4.w, x3, axn);
    }
    const float4* hr4 = reinterpret_cast<const float4*>(WhhT + (size_t)i * H_);
    const float4* hz4 = reinterpret_cast<const float4*>(WhhT + (size_t)(H_ + i) * H_);
    const float4* hn4 = reinterpret_cast<const float4*>(WhhT + (size_t)(2 * H_ + i) * H_);
    const double* sx = sOld + (size_t)b * H_;
    double ahr = 0., ahz = 0., ahn = 0.;
    for (int j = 0; j < 25; ++j) {
      const int q = ks + 8 * j;
      const int e = 4 * q;
      const double s0 = sx[e], s1 = sx[e + 1], s2 = sx[e + 2], s3 = sx[e + 3];
      const float4 r4 = hr4[q], z4 = hz4[q], n4 = hn4[q];
      ahr = fma((double)r4.x, s0, ahr); ahr = fma((double)r4.y, s1, ahr);
      ahr = fma((double)r4.z, s2, ahr); ahr = fma((double)r4.w, s3, ahr);
      ahz = fma((double)z4.x, s0, ahz); ahz = fma((double)z4.y, s1, ahz);
      ahz = fma((double)z4.z, s2, ahz); ahz = fma((double)z4.w, s3, ahz);
      ahn = fma((double)n4.x, s0, ahn); ahn = fma((double)n4.y, s1, ahn);
      ahn = fma((double)n4.z, s2, ahn); ahn = fma((double)n4.w, s3, ahn);
    }
    #pragma unroll
    for (int off = 1; off < 8; off <<= 1) {
      axr += __shfl_xor(axr, off); axz += __shfl_xor(axz, off); axn += __shfl_xor(axn, off);
      ahr += __shfl_xor(ahr, off); ahz += __shfl_xor(ahz, off); ahn += __shfl_xor(ahn, off);
    }
    if (ks == 0) {
      const double xr = axr + (double)b_ih[i], xz = axz + (double)b_ih[H_ + i],
                   xn = axn + (double)b_ih[2 * H_ + i];
      const double hr = ahr + (double)b_hh[i], hz = ahz + (double)b_hh[H_ + i],
                   hn = ahn + (double)b_hh[2 * H_ + i];
      const double r = 1.0 / (1.0 + exp(-(xr + hr)));
      const double z = 1.0 / (1.0 + exp(-(xz + hz)));
      const double n = tanh(xn + r * hn);
      const double sn = (1.0 - z) * n + z * sOld[b * H_ + i];
      sNew[b * H_ + i] = sn;
      res[((size_t)b * L_ + idx) * H_ + i] = (float)sn;
    }
  } else {
    if (idx > 0) {
      const int tsk = (bid - 100) * 8 + wid;     // wave per (b,j)
      const int b = tsk >> 7, j = tsk & (L_ - 1);
      const size_t bj = (size_t)b * L_ + j;
      double e0 = Gd[bj * A_ + lane], e1 = Gd[bj * A_ + lane + 64];
      const double an0 = angD[bj * 3], an1 = angD[bj * 3 + 1], an2 = angD[bj * 3 + 2];
      const double dd0 = dstR[bj * 3], dd1 = dstR[bj * 3 + 1], dd2 = dstR[bj * 3 + 2];
      e0 = fma((double)W1[864 * A_ + lane], an0, e0);
      e0 = fma((double)W1[865 * A_ + lane], an1, e0);
      e0 = fma((double)W1[866 * A_ + lane], an2, e0);
      e0 = fma((double)W1[867 * A_ + lane], dd0, e0);
      e0 = fma((double)W1[868 * A_ + lane], dd1, e0);
      e0 = fma((double)W1[869 * A_ + lane], dd2, e0);
      e1 = fma((double)W1[864 * A_ + lane + 64], an0, e1);
      e1 = fma((double)W1[865 * A_ + lane + 64], an1, e1);
      e1 = fma((double)W1[866 * A_ + lane + 64], an2, e1);
      e1 = fma((double)W1[867 * A_ + lane + 64], dd0, e1);
      e1 = fma((double)W1[868 * A_ + lane + 64], dd1, e1);
      e1 = fma((double)W1[869 * A_ + lane + 64], dd2, e1);
      e0 = tanh(e0); e1 = tanh(e1);
      double lg[8];
      #pragma unroll
      for (int h = 0; h < 8; ++h) {
        double v = fma(e0, (double)W2[lane * 8 + h], e1 * (double)W2[(lane + 64) * 8 + h]);
        #pragma unroll
        for (int off = 1; off < 64; off <<= 1) v += __shfl_xor(v, off);
        lg[h] = v;
      }
      if (lane == 0) {
        const bool valid = (j < idx) && (dd1 <= RAD_);
        double* wrow = wAr + bj * HD_;
        #pragma unroll
        for (int h = 0; h < 8; ++h) wrow[h] = valid ? exp(lg[h]) : 0.0;
      }
    }
  }
}

// ===== KB: pooled (0..127) || G-update (128..135) || angle/pos/dist (136) =====
__global__ __launch_bounds__(NT)
void srnn_b(const float* __restrict__ data, const float* __restrict__ Wa,
            const float* __restrict__ ba, const float* __restrict__ W1,
            float* __restrict__ out, float* __restrict__ ws, int idx)
{
  __shared__ double smd[528];
  const float* res = ws + OF_RES;
  double* wd   = (double*)(ws + FLT_END);
  double* st2  = wd + D_ST;
  double* angD = wd + D_ANG;
  double* posD = wd + D_POS;
  double* dstD = wd + D_DST;
  double* Gd   = wd + D_G;
  double* wAr  = wd + D_W;
  double* pND  = wd + D_PN;

  const int bid = blockIdx.x, tid = threadIdx.x;
  const int rp = idx & 1;
  double* sNew = st2 + (size_t)(rp ^ 1) * B_ * H_;
  const double* dstR = dstD + (size_t)(idx & 1) * (B_ * L_ * 3);
  double* dstW = dstD + (size_t)((idx + 1) & 1) * (B_ * L_ * 3);

  if (bid < 128) {
    if (idx > 0) {                               // per (b, f-slice of 55), all heads
      const int b = bid >> 4, sl = bid & 15;
      const int f0 = sl * 55;
      const int fn = (F_ - f0 < 55) ? (F_ - f0) : 55;
      const int fl = tid >> 3, h = tid & 7;
      if (fl < fn) {
        const int f = f0 + fl;
        const float* fbf = nullptr; const double* fbd = nullptr; int strd = 0;
        if (f < H_)                { fbf = res  + f + (size_t)b * L_ * H_;               strd = H_;  }
        else if (f < H_ + IN_)     { fbf = data + (f - H_) + (size_t)b * L_ * IN_;       strd = IN_; }
        else if (f < H_ + IN_ + 3) { fbd = angD + (f - H_ - IN_) + (size_t)b * L_ * 3;   strd = 3;   }
        else                       { fbd = dstR + (f - H_ - IN_ - 3) + (size_t)b * L_ * 3; strd = 3; }
        const double* wp = wAr + (size_t)b * L_ * HD_ + h;
        double acc = 0.0, zs = 0.0;
        for (int j = 0; j < idx; ++j) {
          const double wj = wp[(size_t)j * HD_];
          zs += wj;
          const double fv = fbf ? (double)fbf[(size_t)j * strd] : fbd[(size_t)j * strd];
          acc = fma(wj, fv, acc);
        }
        pND[(size_t)b * KO_ + (size_t)h * F_ + f] = acc / zs;
      }
    }
  } else if (bid < 136) {
    const int b = bid - 128;                     // G-row update for step idx
    const int a = tid & (A_ - 1), ksl = tid >> 7;
    const double* sr = sNew + (size_t)b * H_;
    const int i0 = ksl * 200;
    double p = 0.0;
    for (int k = 0; k < 200; ++k)
      p = fma(sr[i0 + k], (double)W1[(size_t)(i0 + k) * A_ + a], p);
    smd[tid] = p;
    __syncthreads();
    if (tid < 128)
      Gd[((size_t)b * L_ + idx) * A_ + tid] +=
          smd[tid] + smd[128 + tid] + smd[256 + tid] + smd[384 + tid];
  } else {
    // angle = state@Wa+ba; positions row idx; outputs; dist (parity write)
    const int b7 = tid / 48, rem = tid % 48, t3 = rem / 16, ksl = rem & 15;
    if (tid < 384) {
      const double* sr = sNew + (size_t)b7 * H_;
      const int i0 = ksl * 50;
      double p = 0.0;
      for (int k = 0; k < 50; ++k)
        p = fma(sr[i0 + k], (double)Wa[(i0 + k) * 3 + t3], p);
      smd[tid] = p;
    }
    __syncthreads();
    if (tid < 24) {
      const int b2 = tid / 3, t4 = tid % 3;
      double s = (double)ba[t4];
      for (int u = 0; u < 16; ++u) s += smd[b2 * 48 + t4 * 16 + u];
      smd[384 + tid] = s;
      angD[((size_t)b2 * L_ + idx) * 3 + t4] = s;
      out[(size_t)B_ * L_ * 9 + ((size_t)b2 * L_ + idx) * 3 + t4] = (float)s;
    }
    __syncthreads();
    if (tid < 24) {
      const int b2 = tid / 3, t4 = tid % 3;
      const double a = smd[384 + b2 * 3 + t4];
      const double asum = smd[384 + b2 * 3] + smd[384 + b2 * 3 + 1] + smd[384 + b2 * 3 + 2];
      const double sa = sin(a), ca = cos(a), cs = cos(asum), ss = sin(asum);
      double px = 0., py = 0., pz = 0.;
      if (idx > 0) {
        const double* pr = posD + ((size_t)b2 * L_ + idx - 1) * 9 + t4 * 3;
        px = pr[0]; py = pr[1]; pz = pr[2];
      }
      px = fma(BOND_, ca, px);
      py = fma(BOND_, sa * cs, py);
      pz = fma(BOND_, sa * ss, pz);
      double* pw = posD + ((size_t)b2 * L_ + idx) * 9 + t4 * 3;
      pw[0] = px; pw[1] = py; pw[2] = pz;
      float* ow = out + ((size_t)b2 * L_ + idx) * 9 + t4 * 3;
      ow[0] = (float)px; ow[1] = (float)py; ow[2] = (float)pz;
    }
    __syncthreads();
    if (idx < L_ - 1) {                          // dist rows j<=idx vs positions[idx]
      for (int u = tid; u < 4096; u += NT) {
        const int b = u >> 9, rem2 = u & 511;
        const int j = rem2 >> 2, t6 = rem2 & 3;
        if (t6 < 3 && j <= idx) {
          const double* pa = posD + ((size_t)b * L_ + idx) * 9 + t6 * 3;
          const double* pb = posD + ((size_t)b * L_ + j) * 9 + t6 * 3;
          const double dx = pa[0] - pb[0], dy = pa[1] - pb[1], dz = pa[2] - pb[2];
          dstW[((size_t)b * L_ + j) * 3 + t6] =
              sqrt(fma(dx, dx, fma(dy, dy, fma(dz, dz, 1e-12))));
        }
      }
    }
  }
}

// ============ KC: ctx = pooledN @ Wout + bout (launched for 1<=idx<=126) ============
__global__ __launch_bounds__(NT)
void srnn_c(const float* __restrict__ bout, float* __restrict__ ws)
{
  const float* WoutT = ws + OF_WOT;
  double* wd   = (double*)(ws + FLT_END);
  double* ctxD = wd + D_CTX;
  const double* pND = wd + D_PN;

  const int bid = blockIdx.x, tid = threadIdx.x;
  const int wid = tid >> 6, lane = tid & 63;
  const int c = bid * 8 + wid;                   // wave per output column
  const int b = lane >> 3, ks = lane & 7;
  const float4* wr = reinterpret_cast<const float4*>(WoutT + (size_t)c * KO_);
  const double* pr = pND + (size_t)b * KO_;
  double acc = 0.0;
  for (int j = 0; j < 218; ++j) {
    const int q = ks + 8 * j;
    if (q < 1740) {
      const float4 w4 = wr[q];
      const int e = 4 * q;
      acc = fma((double)w4.x, pr[e],     acc);
      acc = fma((double)w4.y, pr[e + 1], acc);
      acc = fma((double)w4.z, pr[e + 2], acc);
      acc = fma((double)w4.w, pr[e + 3], acc);
    }
  }
  #pragma unroll
  for (int off = 1; off < 8; off <<= 1) acc += __shfl_xor(acc, off);
  if ((lane & 7) == 0)
    ctxD[b * C_ + c] = acc + (double)bout[c];
}

extern "C" void kernel_launch(void* const* d_in, const int* in_sizes, int n_in,
                              void* d_out, int out_size, void* d_ws, size_t ws_size,
                              hipStream_t stream) {
  (void)in_sizes; (void)n_in; (void)out_size;
  if (ws_size < WS_BYTES) return;
  const float* data = (const float*)d_in[0];
  const float* W_ih = (const float*)d_in[1];
  const float* W_hh = (const float*)d_in[2];
  const float* b_ih = (const float*)d_in[3];
  const float* b_hh = (const float*)d_in[4];
  const float* Wa   = (const float*)d_in[5];
  const float* ba   = (const float*)d_in[6];
  const float* W1   = (const float*)d_in[7];
  const float* b1   = (const float*)d_in[8];
  const float* W2   = (const float*)d_in[9];
  const float* Wout = (const float*)d_in[10];
  const float* bout = (const float*)d_in[11];
  float* ws  = (float*)d_ws;
  float* out = (float*)d_out;

  srnn_init<<<dim3(256), dim3(NT), 0, stream>>>(data, W_ih, W_hh, W1, b1, Wout, ws);
  for (int idx = 0; idx < L_; ++idx) {
    srnn_a<<<dim3(228), dim3(NT), 0, stream>>>(data, b_ih, b_hh, W1, W2, ws, idx);
    srnn_b<<<dim3(137), dim3(NT), 0, stream>>>(data, Wa, ba, W1, out, ws, idx);
    if (idx >= 1 && idx <= L_ - 2)
      srnn_c<<<dim3(100), dim3(NT), 0, stream>>>(bout, ws);
  }
}

// Round 9
// 17228.915 us; speedup vs baseline: 1.0162x; 1.0162x over previous
//
#include <hip/hip_runtime.h>
#include <cmath>

namespace {

constexpr int B_ = 8, L_ = 128, IN_ = 64, H_ = 800, C_ = 800, A_ = 128, HD_ = 8;
constexpr int F_ = 870;
constexpr int KX_ = IN_ + C_;          // 864
constexpr int KO_ = HD_ * F_;          // 6960
constexpr double RAD_ = 8.0, BOND_ = 3.8;
constexpr int NB = 256, NT = 512;

// ---- barrier state: first 12 KB of ws (all 128B-line separated) ----
// main arrivals : word (i)*32,      i=0..63   (4 blocks per line)
// main release  : word (64+g)*32,   g=0..7    (32 pollers per line)
// init arrivals : word (72+g)*32
// init release  : word (80+g)*32
// ---- float region of ws (weights transposed + res f32) ----
constexpr size_t OF_RES = 3072;                                 // res [B][L][H] f32
constexpr size_t OF_WIT = OF_RES + (size_t)B_ * L_ * H_;        // W_ih^T [2400][864]
constexpr size_t OF_WHT = OF_WIT + (size_t)3 * H_ * KX_;        // W_hh^T [2400][800]
constexpr size_t OF_WOT = OF_WHT + (size_t)3 * H_ * H_;         // Wout^T [800][6960]
constexpr size_t FLT_END = OF_WOT + (size_t)C_ * KO_;           // even
// ---- double region ----
constexpr size_t D_ST  = 0;                                     // state dbuf [2][B][H]
constexpr size_t D_CTX = D_ST + 2ull * B_ * H_;                 // context [B][C]
constexpr size_t D_ANG = D_CTX + (size_t)B_ * C_;               // angles [B][L][3]
constexpr size_t D_POS = D_ANG + (size_t)B_ * L_ * 3;           // positions [B][L][3][3]
constexpr size_t D_DST = D_POS + (size_t)B_ * L_ * 9;           // dist [2][B][L][3] parity
constexpr size_t D_G   = D_DST + 2ull * B_ * L_ * 3;            // G [B][L][A]
constexpr size_t D_W   = D_G + (size_t)B_ * L_ * A_;            // w [B][L][HD]
constexpr size_t D_PN  = D_W + (size_t)B_ * L_ * HD_;           // pooledN [B][KO]
constexpr size_t D_END = D_PN + (size_t)B_ * KO_;
constexpr size_t WS_BYTES = FLT_END * 4 + D_END * 8;            // ~43.5 MB

// LDS geometry (floats). Type-A (bid<160): 5 neurons + 2 Wout cols.
// Type-B (bid>=160): 5 Wout cols.
constexpr int LD_NEUR = 4992;          // per-neuron: 3*864 ih + 3*800 hh
constexpr int LD_WOUT_A = 24960;       // type-A Wout base (5*4992)
constexpr int LD_TOT = 38880;          // 155,520 B

// ---- coherent-point (agent-scope, relaxed) accessors: bypass per-XCD L2/L1.
__device__ __forceinline__ float ldcf(const float* p) {
  unsigned v = __hip_atomic_load((const unsigned*)p, __ATOMIC_RELAXED,
                                 __HIP_MEMORY_SCOPE_AGENT);
  return __builtin_bit_cast(float, v);
}
__device__ __forceinline__ void stcf(float* p, float x) {
  __hip_atomic_store((unsigned*)p, __builtin_bit_cast(unsigned, x),
                     __ATOMIC_RELAXED, __HIP_MEMORY_SCOPE_AGENT);
}
__device__ __forceinline__ double ldcd(const double* p) {
  unsigned long long v = __hip_atomic_load((const unsigned long long*)p,
                                           __ATOMIC_RELAXED, __HIP_MEMORY_SCOPE_AGENT);
  return __builtin_bit_cast(double, v);
}
__device__ __forceinline__ void stcd(double* p, double x) {
  __hip_atomic_store((unsigned long long*)p,
                     __builtin_bit_cast(unsigned long long, x),
                     __ATOMIC_RELAXED, __HIP_MEMORY_SCOPE_AGENT);
}

// One-time fenced barrier (init): covers the plain-stored transposes/zeros.
__device__ __forceinline__ void gbar_init(unsigned* cnt) {
  asm volatile("s_waitcnt vmcnt(0)" ::: "memory");
  __syncthreads();
  const unsigned grp = (unsigned)blockIdx.x >> 5;
  if (threadIdx.x == 0)
    __hip_atomic_fetch_add(&cnt[(72 + grp) * 32], 1u,
                           __ATOMIC_RELEASE, __HIP_MEMORY_SCOPE_AGENT);
  if (blockIdx.x == 0) {
    if (threadIdx.x < 8) {
      while (__hip_atomic_load(&cnt[(72 + threadIdx.x) * 32],
                               __ATOMIC_RELAXED, __HIP_MEMORY_SCOPE_AGENT) < 32u)
        __builtin_amdgcn_s_sleep(8);
    }
    if (threadIdx.x == 0)
      __builtin_amdgcn_fence(__ATOMIC_ACQUIRE, "agent");
    __syncthreads();
    if (threadIdx.x < 8)
      __hip_atomic_store(&cnt[(80 + threadIdx.x) * 32], 1u,
                         __ATOMIC_RELEASE, __HIP_MEMORY_SCOPE_AGENT);
    __syncthreads();
  } else {
    if (threadIdx.x == 0) {
      while (__hip_atomic_load(&cnt[(80 + grp) * 32],
                               __ATOMIC_RELAXED, __HIP_MEMORY_SCOPE_AGENT) < 1u)
        __builtin_amdgcn_s_sleep(32);
      __builtin_amdgcn_fence(__ATOMIC_ACQUIRE, "agent");
    }
    __syncthreads();
  }
}

// Main-loop barrier: fence-free (all cross-block state is LLC-atomic).
// Anti-contention: 64 arrival lines (4 RMWs each), block-0 aggregates with
// 64 threads at s_sleep(8); waiters poll 8 group flags at s_sleep(32)
// (~0.85us) -- r6/r7's s_sleep(1) polls (~27ns) hammered the LLC with
// ~9 loads/ns and congested every coherent-point access (the ~35us/unit).
__device__ __forceinline__ void gbarf(unsigned* cnt, unsigned& ep) {
  ++ep;
  asm volatile("s_waitcnt vmcnt(0)" ::: "memory");
  __syncthreads();
  if (threadIdx.x == 0)
    __hip_atomic_fetch_add(&cnt[(blockIdx.x & 63) * 32], 1u,
                           __ATOMIC_RELAXED, __HIP_MEMORY_SCOPE_AGENT);
  if (blockIdx.x == 0) {
    if (threadIdx.x < 64) {
      const unsigned tgt = ep * 4u;
      while (__hip_atomic_load(&cnt[threadIdx.x * 32],
                               __ATOMIC_RELAXED, __HIP_MEMORY_SCOPE_AGENT) < tgt)
        __builtin_amdgcn_s_sleep(8);
    }
    __syncthreads();
    if (threadIdx.x < 8)
      __hip_atomic_store(&cnt[(64 + threadIdx.x) * 32], ep,
                         __ATOMIC_RELAXED, __HIP_MEMORY_SCOPE_AGENT);
  } else {
    if (threadIdx.x == 0) {
      while (__hip_atomic_load(&cnt[(64 + ((unsigned)blockIdx.x >> 5)) * 32],
                               __ATOMIC_RELAXED, __HIP_MEMORY_SCOPE_AGENT) < ep)
        __builtin_amdgcn_s_sleep(32);
    }
    __syncthreads();
  }
}

__device__ void transp(const float* __restrict__ src, float* __restrict__ dst,
                       int R, int Cn, float* sm) {
  const int tr_ = (R + 31) >> 5, tc_ = (Cn + 31) >> 5;
  for (int t = blockIdx.x; t < tr_ * tc_; t += gridDim.x) {
    const int r0 = (t / tc_) << 5, c0 = (t % tc_) << 5;
    __syncthreads();
    for (int e = threadIdx.x; e < 1024; e += NT) {
      const int rr = e >> 5, cc = e & 31, r = r0 + rr, c = c0 + cc;
      sm[rr * 33 + cc] = (r < R && c < Cn) ? src[(size_t)r * Cn + c] : 0.0f;
    }
    __syncthreads();
    for (int e = threadIdx.x; e < 1024; e += NT) {
      const int cc = e >> 5, rr = e & 31, r = r0 + rr, c = c0 + cc;
      if (r < R && c < Cn) dst[(size_t)c * R + r] = sm[rr * 33 + cc];
    }
  }
}

} // namespace

extern "C" __global__ __launch_bounds__(NT, 1)
void srnn(const float* __restrict__ data, const float* __restrict__ W_ih,
          const float* __restrict__ W_hh, const float* __restrict__ b_ih,
          const float* __restrict__ b_hh, const float* __restrict__ Wa,
          const float* __restrict__ ba, const float* __restrict__ W1,
          const float* __restrict__ b1, const float* __restrict__ W2,
          const float* __restrict__ Wout, const float* __restrict__ bout,
          float* __restrict__ out, float* __restrict__ ws)
{
  __shared__ __align__(16) float wlds[LD_TOT];   // 155,520 B persistent weights
  __shared__ double smd[528];                    // 4,224 B scratch (1056 floats)
  float* smf = (float*)smd;
  unsigned* cnt = (unsigned*)ws;
  float* res   = ws + OF_RES;
  float* WihT  = ws + OF_WIT;
  float* WhhT  = ws + OF_WHT;
  float* WoutT = ws + OF_WOT;
  double* wd   = (double*)(ws + FLT_END);
  double* st2  = wd + D_ST;
  double* ctxD = wd + D_CTX;
  double* angD = wd + D_ANG;
  double* posD = wd + D_POS;
  double* dstD = wd + D_DST;                     // [2][B][L][3]
  double* Gd   = wd + D_G;
  double* wAr  = wd + D_W;
  double* pND  = wd + D_PN;

  const int bid = blockIdx.x, tid = threadIdx.x;
  const int wid = tid >> 6, lane = tid & 63;
  unsigned ep = 0;

  // ================= init (fenced barrier covers these plain stores) ======
  for (int i = bid * NT + tid; i < (int)(D_ANG - D_ST); i += NB * NT)
    wd[i] = 0.0;
  {
    const int i = bid * NT + tid;                // B*L*A == NB*NT
    const int a = i & (A_ - 1);
    const int bj = i >> 7;
    double acc = (double)b1[a];
    const float* dr = data + (size_t)bj * IN_;
    #pragma unroll 8
    for (int k = 0; k < IN_; ++k)
      acc = fma((double)dr[k], (double)W1[(size_t)(H_ + k) * A_ + a], acc);
    Gd[i] = acc;
  }
  transp(W_ih, WihT, KX_, 3 * H_, smf);
  transp(W_hh, WhhT, H_, 3 * H_, smf);
  transp(Wout, WoutT, KO_, C_, smf);
  gbar_init(cnt);

  // ---- load persistent LDS weight slices (coalesced, from transposed) ----
  if (bid < 160) {
    for (int rg = 0; rg < 15; ++rg) {            // ih rows: 5 neurons x 3 gates
      const int s = rg / 3, g = rg % 3;
      const int i = bid * 5 + s;
      const float4* src = reinterpret_cast<const float4*>(WihT + (size_t)(g * H_ + i) * KX_);
      float4* dst = reinterpret_cast<float4*>(&wlds[s * LD_NEUR + g * 864]);
      for (int k4 = tid; k4 < 216; k4 += NT) dst[k4] = src[k4];
    }
    for (int rg = 0; rg < 15; ++rg) {            // hh rows
      const int s = rg / 3, g = rg % 3;
      const int i = bid * 5 + s;
      const float4* src = reinterpret_cast<const float4*>(WhhT + (size_t)(g * H_ + i) * H_);
      float4* dst = reinterpret_cast<float4*>(&wlds[s * LD_NEUR + 2592 + g * 800]);
      for (int k4 = tid; k4 < 200; k4 += NT) dst[k4] = src[k4];
    }
    for (int cs = 0; cs < 2; ++cs) {             // 2 Wout cols
      const int c = bid * 2 + cs;
      const float4* src = reinterpret_cast<const float4*>(WoutT + (size_t)c * KO_);
      float4* dst = reinterpret_cast<float4*>(&wlds[LD_WOUT_A + cs * KO_]);
      for (int k4 = tid; k4 < 1740; k4 += NT) dst[k4] = src[k4];
    }
  } else {
    for (int cs = 0; cs < 5; ++cs) {             // 5 Wout cols
      const int c = 320 + (bid - 160) * 5 + cs;
      const float4* src = reinterpret_cast<const float4*>(WoutT + (size_t)c * KO_);
      float4* dst = reinterpret_cast<float4*>(&wlds[cs * KO_]);
      for (int k4 = tid; k4 < 1740; k4 += NT) dst[k4] = src[k4];
    }
  }
  __syncthreads();

  // ================= 128 steps, 3 fence-free barriers each =================
  for (int idx = 0; idx < L_; ++idx) {
    const int rp = idx & 1;
    const double* sOld = st2 + (size_t)rp * B_ * H_;
    double* sNew = st2 + (size_t)(rp ^ 1) * B_ * H_;
    const double* dstR = dstD + (size_t)(idx & 1) * (B_ * L_ * 3);       // read buf
    double* dstW = dstD + (size_t)((idx + 1) & 1) * (B_ * L_ * 3);       // write buf

    // ---- P1: GRU (type-A waves 0..4) || e/logits/w (remaining 1024 waves) ----
    if (bid < 160 && wid < 5) {
      const int i = bid * 5 + wid;               // neuron
      const int b = lane >> 3, ks = lane & 7;
      const float4* wr4 = reinterpret_cast<const float4*>(&wlds[wid * LD_NEUR]);
      const float4* wz4 = reinterpret_cast<const float4*>(&wlds[wid * LD_NEUR + 864]);
      const float4* wn4 = reinterpret_cast<const float4*>(&wlds[wid * LD_NEUR + 1728]);
      const float4* dx4 = reinterpret_cast<const float4*>(data + ((size_t)b * L_ + idx) * IN_);
      const double* cx = ctxD + (size_t)b * C_;
      double axr = 0., axz = 0., axn = 0.;
      #pragma unroll
      for (int j = 0; j < 2; ++j) {
        const int q = ks + 8 * j;
        const float4 x4 = dx4[q];
        const float4 r4 = wr4[q], z4 = wz4[q], n4 = wn4[q];
        const double x0 = x4.x, x1 = x4.y, x2 = x4.z, x3 = x4.w;
        axr = fma((double)r4.x, x0, axr); axr = fma((double)r4.y, x1, axr);
        axr = fma((double)r4.z, x2, axr); axr = fma((double)r4.w, x3, axr);
        axz = fma((double)z4.x, x0, axz); axz = fma((double)z4.y, x1, axz);
        axz = fma((double)z4.z, x2, axz); axz = fma((double)z4.w, x3, axz);
        axn = fma((double)n4.x, x0, axn); axn = fma((double)n4.y, x1, axn);
        axn = fma((double)n4.z, x2, axn); axn = fma((double)n4.w, x3, axn);
      }
      for (int j = 2; j < 27; ++j) {
        const int q = ks + 8 * j;
        const int e = 4 * q - 64;
        const double x0 = ldcd(cx + e),     x1 = ldcd(cx + e + 1),
                     x2 = ldcd(cx + e + 2), x3 = ldcd(cx + e + 3);
        const float4 r4 = wr4[q], z4 = wz4[q], n4 = wn4[q];
        axr = fma((double)r4.x, x0, axr); axr = fma((double)r4.y, x1, axr);
        axr = fma((double)r4.z, x2, axr); axr = fma((double)r4.w, x3, axr);
        axz = fma((double)z4.x, x0, axz); axz = fma((double)z4.y, x1, axz);
        axz = fma((double)z4.z, x2, axz); axz = fma((double)z4.w, x3, axz);
        axn = fma((double)n4.x, x0, axn); axn = fma((double)n4.y, x1, axn);
        axn = fma((double)n4.z, x2, axn); axn = fma((double)n4.w, x3, axn);
      }
      const float4* hr4 = reinterpret_cast<const float4*>(&wlds[wid * LD_NEUR + 2592]);
      const float4* hz4 = reinterpret_cast<const float4*>(&wlds[wid * LD_NEUR + 2592 + 800]);
      const float4* hn4 = reinterpret_cast<const float4*>(&wlds[wid * LD_NEUR + 2592 + 1600]);
      const double* sx = sOld + (size_t)b * H_;
      double ahr = 0., ahz = 0., ahn = 0.;
      for (int j = 0; j < 25; ++j) {
        const int q = ks + 8 * j;
        const int e = 4 * q;
        const double s0 = ldcd(sx + e),     s1 = ldcd(sx + e + 1),
                     s2 = ldcd(sx + e + 2), s3 = ldcd(sx + e + 3);
        const float4 r4 = hr4[q], z4 = hz4[q], n4 = hn4[q];
        ahr = fma((double)r4.x, s0, ahr); ahr = fma((double)r4.y, s1, ahr);
        ahr = fma((double)r4.z, s2, ahr); ahr = fma((double)r4.w, s3, ahr);
        ahz = fma((double)z4.x, s0, ahz); ahz = fma((double)z4.y, s1, ahz);
        ahz = fma((double)z4.z, s2, ahz); ahz = fma((double)z4.w, s3, ahz);
        ahn = fma((double)n4.x, s0, ahn); ahn = fma((double)n4.y, s1, ahn);
        ahn = fma((double)n4.z, s2, ahn); ahn = fma((double)n4.w, s3, ahn);
      }
      #pragma unroll
      for (int off = 1; off < 8; off <<= 1) {
        axr += __shfl_xor(axr, off); axz += __shfl_xor(axz, off); axn += __shfl_xor(axn, off);
        ahr += __shfl_xor(ahr, off); ahz += __shfl_xor(ahz, off); ahn += __shfl_xor(ahn, off);
      }
      if (ks == 0) {
        const double xr = axr + (double)b_ih[i], xz = axz + (double)b_ih[H_ + i],
                     xn = axn + (double)b_ih[2 * H_ + i];
        const double hr = ahr + (double)b_hh[i], hz = ahz + (double)b_hh[H_ + i],
                     hn = ahn + (double)b_hh[2 * H_ + i];
        const double r = 1.0 / (1.0 + exp(-(xr + hr)));
        const double z = 1.0 / (1.0 + exp(-(xz + hz)));
        const double n = tanh(xn + r * hn);
        const double sn = (1.0 - z) * n + z * ldcd(sOld + b * H_ + i);
        stcd(sNew + b * H_ + i, sn);
        stcf(res + ((size_t)b * L_ + idx) * H_ + i, (float)sn);
      }
    } else {
      int tsk = -1;
      if (bid >= 160) tsk = (bid - 160) * 8 + wid;          // 0..767
      else tsk = 768 + bid * 3 + (wid - 5);                  // 768..1247
      if (tsk < 1024 && idx > 0) {
        const int b = tsk >> 7, j = tsk & (L_ - 1);
        if (j < idx) {                           // guard: skip future rows entirely
          const size_t bj = (size_t)b * L_ + j;
          double e0 = ldcd(Gd + bj * A_ + lane), e1 = ldcd(Gd + bj * A_ + lane + 64);
          const double an0 = ldcd(angD + bj * 3),     an1 = ldcd(angD + bj * 3 + 1),
                       an2 = ldcd(angD + bj * 3 + 2);
          const double dd0 = ldcd(dstR + bj * 3),     dd1 = ldcd(dstR + bj * 3 + 1),
                       dd2 = ldcd(dstR + bj * 3 + 2);
          e0 = fma((double)W1[864 * A_ + lane], an0, e0);
          e0 = fma((double)W1[865 * A_ + lane], an1, e0);
          e0 = fma((double)W1[866 * A_ + lane], an2, e0);
          e0 = fma((double)W1[867 * A_ + lane], dd0, e0);
          e0 = fma((double)W1[868 * A_ + lane], dd1, e0);
          e0 = fma((double)W1[869 * A_ + lane], dd2, e0);
          e1 = fma((double)W1[864 * A_ + lane + 64], an0, e1);
          e1 = fma((double)W1[865 * A_ + lane + 64], an1, e1);
          e1 = fma((double)W1[866 * A_ + lane + 64], an2, e1);
          e1 = fma((double)W1[867 * A_ + lane + 64], dd0, e1);
          e1 = fma((double)W1[868 * A_ + lane + 64], dd1, e1);
          e1 = fma((double)W1[869 * A_ + lane + 64], dd2, e1);
          e0 = tanh(e0); e1 = tanh(e1);
          double lg[8];
          #pragma unroll
          for (int h = 0; h < 8; ++h) {
            double v = fma(e0, (double)W2[lane * 8 + h], e1 * (double)W2[(lane + 64) * 8 + h]);
            #pragma unroll
            for (int off = 1; off < 64; off <<= 1) v += __shfl_xor(v, off);
            lg[h] = v;
          }
          if (lane == 0) {
            const bool valid = (dd1 <= RAD_);
            double* wrow = wAr + bj * HD_;
            #pragma unroll
            for (int h = 0; h < 8; ++h) stcd(wrow + h, valid ? exp(lg[h]) : 0.0);
          }
        }
      }
    }
    gbarf(cnt, ep);

    // ---- P2: pooled (0..127) || G-update (128..135) || angle+pos+dist (136) ----
    if (bid < 128) {
      if (idx > 0) {                             // per (b, f-slice of 55), all 8 heads
        const int b = bid >> 4, sl = bid & 15;
        const int f0 = sl * 55;
        const int fn = (F_ - f0 < 55) ? (F_ - f0) : 55;
        const int fl = tid >> 3, h = tid & 7;
        if (fl < fn) {
          const int f = f0 + fl;
          int kind; const float* fbf = nullptr; const double* fbd = nullptr; int strd = 0;
          if (f < H_)                { kind = 0; fbf = res  + f + (size_t)b * L_ * H_;               strd = H_;  }
          else if (f < H_ + IN_)     { kind = 1; fbf = data + (f - H_) + (size_t)b * L_ * IN_;       strd = IN_; }
          else if (f < H_ + IN_ + 3) { kind = 2; fbd = angD + (f - H_ - IN_) + (size_t)b * L_ * 3;   strd = 3;   }
          else                       { kind = 2; fbd = dstR + (f - H_ - IN_ - 3) + (size_t)b * L_ * 3; strd = 3; }
          const double* wp = wAr + (size_t)b * L_ * HD_ + h;
          double acc = 0.0, zs = 0.0;
          for (int j = 0; j < idx; ++j) {
            const double wj = ldcd(wp + (size_t)j * HD_);
            zs += wj;
            const double fv = (kind == 0) ? (double)ldcf(fbf + (size_t)j * strd)
                            : (kind == 1) ? (double)fbf[(size_t)j * strd]
                                          : ldcd(fbd + (size_t)j * strd);
            acc = fma(wj, fv, acc);
          }
          stcd(pND + (size_t)b * KO_ + (size_t)h * F_ + f, acc / zs);
        }
      }
    } else if (bid < 136) {
      const int b = bid - 128;                   // G-row update for step idx
      const int a = tid & (A_ - 1), ksl = tid >> 7;
      const double* sr = sNew + (size_t)b * H_;
      const int i0 = ksl * 200;
      double p = 0.0;
      for (int k = 0; k < 200; ++k)
        p = fma(ldcd(sr + i0 + k), (double)W1[(size_t)(i0 + k) * A_ + a], p);
      smd[tid] = p;
      __syncthreads();
      if (tid < 128) {
        double* gp = Gd + ((size_t)b * L_ + idx) * A_ + tid;
        const double g = ldcd(gp);
        stcd(gp, g + (smd[tid] + smd[128 + tid] + smd[256 + tid] + smd[384 + tid]));
      }
    } else if (bid == 136) {
      // angle = state@Wa+ba; positions row idx; outputs; dist (parity write)
      const int b7 = tid / 48, rem = tid % 48, t3 = rem / 16, ksl = rem & 15;
      if (tid < 384) {
        const double* sr = sNew + (size_t)b7 * H_;
        const int i0 = ksl * 50;
        double p = 0.0;
        for (int k = 0; k < 50; ++k)
          p = fma(ldcd(sr + i0 + k), (double)Wa[(i0 + k) * 3 + t3], p);
        smd[tid] = p;
      }
      __syncthreads();
      if (tid < 24) {
        const int b2 = tid / 3, t4 = tid % 3;
        double s = (double)ba[t4];
        for (int u = 0; u < 16; ++u) s += smd[b2 * 48 + t4 * 16 + u];
        smd[384 + tid] = s;
        stcd(angD + ((size_t)b2 * L_ + idx) * 3 + t4, s);
        out[(size_t)B_ * L_ * 9 + ((size_t)b2 * L_ + idx) * 3 + t4] = (float)s;
      }
      __syncthreads();
      if (tid < 24) {
        const int b2 = tid / 3, t4 = tid % 3;
        const double a = smd[384 + b2 * 3 + t4];
        const double asum = smd[384 + b2 * 3] + smd[384 + b2 * 3 + 1] + smd[384 + b2 * 3 + 2];
        const double sa = sin(a), ca = cos(a), cs = cos(asum), ss = sin(asum);
        double px = 0., py = 0., pz = 0.;
        if (idx > 0) {
          const double* pr = posD + ((size_t)b2 * L_ + idx - 1) * 9 + t4 * 3;
          px = pr[0]; py = pr[1]; pz = pr[2];
        }
        px = fma(BOND_, ca, px);
        py = fma(BOND_, sa * cs, py);
        pz = fma(BOND_, sa * ss, pz);
        double* pw = posD + ((size_t)b2 * L_ + idx) * 9 + t4 * 3;
        pw[0] = px; pw[1] = py; pw[2] = pz;        // posD private to this block
        float* ow = out + ((size_t)b2 * L_ + idx) * 9 + t4 * 3;
        ow[0] = (float)px; ow[1] = (float)py; ow[2] = (float)pz;
      }
      __syncthreads();
      if (idx < L_ - 1) {                        // dist rows j<=idx vs positions[idx]
        for (int u = tid; u < 4096; u += NT) {
          const int b = u >> 9, rem2 = u & 511;
          const int j = rem2 >> 2, t6 = rem2 & 3;
          if (t6 < 3 && j <= idx) {
            const double* pa = posD + ((size_t)b * L_ + idx) * 9 + t6 * 3;
            const double* pb = posD + ((size_t)b * L_ + j) * 9 + t6 * 3;
            const double dx = pa[0] - pb[0], dy = pa[1] - pb[1], dz = pa[2] - pb[2];
            stcd(dstW + ((size_t)b * L_ + j) * 3 + t6,
                 sqrt(fma(dx, dx, fma(dy, dy, fma(dz, dz, 1e-12)))));
          }
        }
      }
    }
    gbarf(cnt, ep);

    // ---- P3: ctx = pooledN @ Wout(LDS cols) + bout ----
    if (idx < L_ - 1) {
      const int ntask = (bid < 160) ? 2 : 5;     // tasks per wave = cols per block
      for (int u = 0; u < ntask; ++u) {
        const int t = wid + 8 * u;
        const int cs = t >> 3, b = t & 7;
        const int c = (bid < 160) ? (bid * 2 + cs) : (320 + (bid - 160) * 5 + cs);
        const int cbase = ((bid < 160) ? LD_WOUT_A : 0) + cs * KO_;
        double acc = 0.0;
        if (idx > 0) {
          const double* pr = pND + (size_t)b * KO_;
          for (int m = 0; m < 28; ++m) {
            const int q = lane + 64 * m;
            if (q < 1740) {
              const float4 w4 = *reinterpret_cast<const float4*>(&wlds[cbase + 4 * q]);
              const int e = 4 * q;
              acc = fma((double)w4.x, ldcd(pr + e),     acc);
              acc = fma((double)w4.y, ldcd(pr + e + 1), acc);
              acc = fma((double)w4.z, ldcd(pr + e + 2), acc);
              acc = fma((double)w4.w, ldcd(pr + e + 3), acc);
            }
          }
          #pragma unroll
          for (int off = 1; off < 64; off <<= 1) acc += __shfl_xor(acc, off);
        }
        if (lane == 0)
          stcd(ctxD + b * C_ + c, (idx > 0) ? (acc + (double)bout[c]) : 0.0);
      }
    }
    gbarf(cnt, ep);
  }
}

extern "C" void kernel_launch(void* const* d_in, const int* in_sizes, int n_in,
                              void* d_out, int out_size, void* d_ws, size_t ws_size,
                              hipStream_t stream) {
  (void)in_sizes; (void)n_in; (void)out_size;
  if (ws_size < WS_BYTES) return;
  const float* data = (const float*)d_in[0];
  const float* W_ih = (const float*)d_in[1];
  const float* W_hh = (const float*)d_in[2];
  const float* b_ih = (const float*)d_in[3];
  const float* b_hh = (const float*)d_in[4];
  const float* Wa   = (const float*)d_in[5];
  const float* ba   = (const float*)d_in[6];
  const float* W1   = (const float*)d_in[7];
  const float* b1   = (const float*)d_in[8];
  const float* W2   = (const float*)d_in[9];
  const float* Wout = (const float*)d_in[10];
  const float* bout = (const float*)d_in[11];
  hipMemsetAsync(d_ws, 0, 12288, stream);        // reset barrier state (replay-safe)
  srnn<<<dim3(NB), dim3(NT), 0, stream>>>(data, W_ih, W_hh, b_ih, b_hh, Wa, ba,
                                          W1, b1, W2, Wout, bout,
                                          (float*)d_out, (float*)d_ws);
}

// Round 10
// 11381.507 us; speedup vs baseline: 1.5383x; 1.5138x over previous
//
#include <hip/hip_runtime.h>
#include <cmath>

namespace {

constexpr int B_ = 8, L_ = 128, IN_ = 64, H_ = 800, C_ = 800, A_ = 128, HD_ = 8;
constexpr int F_ = 870;
constexpr int KX_ = IN_ + C_;          // 864
constexpr int KO_ = HD_ * F_;          // 6960
constexpr double RAD_ = 8.0, BOND_ = 3.8;
constexpr int NB = 256, NT = 512;

// ---- barrier state: first 8 KB of ws, 128B-line granular ----
// line 0-7  : main arrival counter per XCD      cnt[xcc*32]
// line 8    : main done counter                 cnt[256]
// line 16-23: per-XCD block count (init-time)   cnt[(16+x)*32]
// line 24-31: init-barrier arrivals             cnt[(24+g)*32]
// line 32-39: init-barrier release flags        cnt[(32+g)*32]
constexpr size_t OF_RES = 2048;                                 // res [B][L][H] f32
constexpr size_t FLT_END = OF_RES + (size_t)B_ * L_ * H_;       // 821,248 (even)
// ---- double region ----
constexpr size_t D_ST  = 0;                                     // state dbuf [2][B][H]
constexpr size_t D_CTX = D_ST + 2ull * B_ * H_;                 // context [B][C]
constexpr size_t D_ANG = D_CTX + (size_t)B_ * C_;               // angles [B][L][3]
constexpr size_t D_POS = D_ANG + (size_t)B_ * L_ * 3;           // positions [B][L][3][3]
constexpr size_t D_DST = D_POS + (size_t)B_ * L_ * 9;           // dist [2][B][L][3] parity
constexpr size_t D_G   = D_DST + 2ull * B_ * L_ * 3;            // G [B][L][A]
constexpr size_t D_W   = D_G + (size_t)B_ * L_ * A_;            // w [B][L][HD]
constexpr size_t D_PN  = D_W + (size_t)B_ * L_ * HD_;           // pooledN [B][KO]
constexpr size_t D_END = D_PN + (size_t)B_ * KO_;
constexpr size_t WS_BYTES = FLT_END * 4 + D_END * 8;            // ~5.2 MB

// LDS geometry (floats). Type-A (bid<160): 5 neurons + 2 Wout cols.
// Type-B (bid>=160): 5 Wout cols.
constexpr int LD_NEUR = 4992;          // per-neuron: 3*864 ih + 3*800 hh
constexpr int LD_WOUT_A = 24960;       // type-A Wout base (5*4992)
constexpr int LD_TOT = 38880;          // 155,520 B

// One-time init barrier (r6-proven form: release adds + per-block acquire).
__device__ __forceinline__ void gbar_init(unsigned* cnt) {
  __syncthreads();
  const unsigned grp = (unsigned)blockIdx.x >> 5;
  if (threadIdx.x == 0)
    __hip_atomic_fetch_add(&cnt[(24 + grp) * 32], 1u,
                           __ATOMIC_RELEASE, __HIP_MEMORY_SCOPE_AGENT);
  if (blockIdx.x == 0) {
    if (threadIdx.x < 8) {
      while (__hip_atomic_load(&cnt[(24 + threadIdx.x) * 32],
                               __ATOMIC_RELAXED, __HIP_MEMORY_SCOPE_AGENT) < 32u)
        __builtin_amdgcn_s_sleep(8);
    }
    if (threadIdx.x == 0)
      __builtin_amdgcn_fence(__ATOMIC_ACQUIRE, "agent");
    __syncthreads();
    if (threadIdx.x < 8)
      __hip_atomic_store(&cnt[(32 + threadIdx.x) * 32], 1u,
                         __ATOMIC_RELEASE, __HIP_MEMORY_SCOPE_AGENT);
    __syncthreads();
  } else {
    if (threadIdx.x == 0) {
      while (__hip_atomic_load(&cnt[(32 + grp) * 32],
                               __ATOMIC_RELAXED, __HIP_MEMORY_SCOPE_AGENT) < 1u)
        __builtin_amdgcn_s_sleep(8);
      __builtin_amdgcn_fence(__ATOMIC_ACQUIRE, "agent");
    }
    __syncthreads();
  }
}

// Main-loop barrier: ONE buffer_wbl2 per XCD per barrier (the last arriver on
// each XCD elects itself via its per-XCD counter and issues a single
// fence(RELEASE,agent) that writes back the WHOLE XCD L2 -- covering all 32
// resident blocks' dirty lines). r6 issued 256 wbl2 walks/barrier (serialized
// ~32 deep per TCC = the ~33us/unit cost). Acquire stays per-block
// (flash-invalidate, cheap). Arrival/done counters are relaxed LLC atomics.
__device__ __forceinline__ void gbarx(unsigned* cnt, unsigned& ep,
                                      unsigned xcc, unsigned xcnt, unsigned nx) {
  ++ep;
  __syncthreads();                               // drains all waves' vmcnt
  if (threadIdx.x == 0) {
    const unsigned old = __hip_atomic_fetch_add(&cnt[xcc * 32], 1u,
                             __ATOMIC_RELAXED, __HIP_MEMORY_SCOPE_AGENT);
    if (old == ep * xcnt - 1u) {                 // last arriver on this XCD
      __builtin_amdgcn_fence(__ATOMIC_RELEASE, "agent");   // ONE wbl2 / XCD
      __hip_atomic_fetch_add(&cnt[256], 1u,
                             __ATOMIC_RELAXED, __HIP_MEMORY_SCOPE_AGENT);
    }
    while (__hip_atomic_load(&cnt[256],
                             __ATOMIC_RELAXED, __HIP_MEMORY_SCOPE_AGENT) < ep * nx)
      __builtin_amdgcn_s_sleep(8);
    __builtin_amdgcn_fence(__ATOMIC_ACQUIRE, "agent");
  }
  __syncthreads();
}

} // namespace

extern "C" __global__ __launch_bounds__(NT, 1)
void srnn(const float* __restrict__ data, const float* __restrict__ W_ih,
          const float* __restrict__ W_hh, const float* __restrict__ b_ih,
          const float* __restrict__ b_hh, const float* __restrict__ Wa,
          const float* __restrict__ ba, const float* __restrict__ W1,
          const float* __restrict__ b1, const float* __restrict__ W2,
          const float* __restrict__ Wout, const float* __restrict__ bout,
          float* __restrict__ out, float* __restrict__ ws)
{
  __shared__ __align__(16) float wlds[LD_TOT];   // 155,520 B persistent weights
  __shared__ double smd[528];                    // 4,224 B scratch
  __shared__ unsigned s_xcc, s_xcnt, s_nx;
  unsigned* cnt = (unsigned*)ws;
  float* res   = ws + OF_RES;
  double* wd   = (double*)(ws + FLT_END);
  double* st2  = wd + D_ST;
  double* ctxD = wd + D_CTX;
  double* angD = wd + D_ANG;
  double* posD = wd + D_POS;
  double* dstD = wd + D_DST;                     // [2][B][L][3]
  double* Gd   = wd + D_G;
  double* wAr  = wd + D_W;
  double* pND  = wd + D_PN;

  const int bid = blockIdx.x, tid = threadIdx.x;
  const int wid = tid >> 6, lane = tid & 63;
  unsigned ep = 0;

  // ---- XCD discovery (m09: HW_REG_XCC_ID verified on gfx950) ----
  if (tid == 0) {
    unsigned x;
    asm volatile("s_getreg_b32 %0, hwreg(HW_REG_XCC_ID)" : "=s"(x));
    x &= 7u;
    s_xcc = x;
    __hip_atomic_fetch_add(&cnt[(16 + x) * 32], 1u,
                           __ATOMIC_RELAXED, __HIP_MEMORY_SCOPE_AGENT);
  }

  // ================= init (covered by fenced gbar_init) =================
  for (int i = bid * NT + tid; i < (int)(D_ANG - D_ST); i += NB * NT)
    wd[i] = 0.0;                                 // state dbuf + ctx = 0
  {
    const int i = bid * NT + tid;                // B*L*A == NB*NT
    const int a = i & (A_ - 1);
    const int bj = i >> 7;
    double acc = (double)b1[a];
    const float* dr = data + (size_t)bj * IN_;
    #pragma unroll 8
    for (int k = 0; k < IN_; ++k)
      acc = fma((double)dr[k], (double)W1[(size_t)(H_ + k) * A_ + a], acc);
    Gd[i] = acc;
  }
  // ---- persistent LDS weight slices, read DIRECTLY (strided, once) ----
  if (bid < 160) {
    for (int e = tid; e < 5 * 3 * 864; e += NT) {          // ih rows
      const int s = e / 2592, rem = e % 2592, g = rem / 864, k = rem % 864;
      wlds[s * LD_NEUR + g * 864 + k] =
          W_ih[(size_t)k * (3 * H_) + g * H_ + bid * 5 + s];
    }
    for (int e = tid; e < 5 * 3 * 800; e += NT) {          // hh rows
      const int s = e / 2400, rem = e % 2400, g = rem / 800, k = rem % 800;
      wlds[s * LD_NEUR + 2592 + g * 800 + k] =
          W_hh[(size_t)k * (3 * H_) + g * H_ + bid * 5 + s];
    }
    for (int e = tid; e < 2 * KO_; e += NT) {              // 2 Wout cols
      const int cs = e / KO_, k = e % KO_;
      wlds[LD_WOUT_A + cs * KO_ + k] = Wout[(size_t)k * C_ + bid * 2 + cs];
    }
  } else {
    for (int e = tid; e < 5 * KO_; e += NT) {              // 5 Wout cols
      const int cs = e / KO_, k = e % KO_;
      wlds[cs * KO_ + k] = Wout[(size_t)k * C_ + 320 + (bid - 160) * 5 + cs];
    }
  }
  gbar_init(cnt);

  // ---- read back XCD census (stable after init barrier) ----
  if (tid == 0) {
    unsigned n = 0;
    for (int k = 0; k < 8; ++k)
      n += (__hip_atomic_load(&cnt[(16 + k) * 32],
                              __ATOMIC_RELAXED, __HIP_MEMORY_SCOPE_AGENT) > 0u);
    s_nx = n;
    s_xcnt = __hip_atomic_load(&cnt[(16 + s_xcc) * 32],
                               __ATOMIC_RELAXED, __HIP_MEMORY_SCOPE_AGENT);
  }
  __syncthreads();
  const unsigned xcc = s_xcc, xcnt = s_xcnt, nx = s_nx;

  // ================= 128 steps, 3 barriers each =================
  for (int idx = 0; idx < L_; ++idx) {
    const int rp = idx & 1;
    const double* sOld = st2 + (size_t)rp * B_ * H_;
    double* sNew = st2 + (size_t)(rp ^ 1) * B_ * H_;
    const double* dstR = dstD + (size_t)(idx & 1) * (B_ * L_ * 3);       // read
    double* dstW = dstD + (size_t)((idx + 1) & 1) * (B_ * L_ * 3);       // write

    // ---- P1: GRU (type-A waves 0..4) || e/logits/w (1024 waves) ----
    if (bid < 160 && wid < 5) {
      const int i = bid * 5 + wid;               // neuron
      const int b = lane >> 3, ks = lane & 7;
      const float4* wr4 = reinterpret_cast<const float4*>(&wlds[wid * LD_NEUR]);
      const float4* wz4 = reinterpret_cast<const float4*>(&wlds[wid * LD_NEUR + 864]);
      const float4* wn4 = reinterpret_cast<const float4*>(&wlds[wid * LD_NEUR + 1728]);
      const float4* dx4 = reinterpret_cast<const float4*>(data + ((size_t)b * L_ + idx) * IN_);
      const double* cx = ctxD + (size_t)b * C_;
      double axr = 0., axz = 0., axn = 0.;
      #pragma unroll
      for (int j = 0; j < 2; ++j) {
        const int q = ks + 8 * j;
        const float4 x4 = dx4[q];
        const float4 r4 = wr4[q], z4 = wz4[q], n4 = wn4[q];
        const double x0 = x4.x, x1 = x4.y, x2 = x4.z, x3 = x4.w;
        axr = fma((double)r4.x, x0, axr); axr = fma((double)r4.y, x1, axr);
        axr = fma((double)r4.z, x2, axr); axr = fma((double)r4.w, x3, axr);
        axz = fma((double)z4.x, x0, axz); axz = fma((double)z4.y, x1, axz);
        axz = fma((double)z4.z, x2, axz); axz = fma((double)z4.w, x3, axz);
        axn = fma((double)n4.x, x0, axn); axn = fma((double)n4.y, x1, axn);
        axn = fma((double)n4.z, x2, axn); axn = fma((double)n4.w, x3, axn);
      }
      for (int j = 2; j < 27; ++j) {
        const int q = ks + 8 * j;
        const int e = 4 * q - 64;
        const double x0 = cx[e], x1 = cx[e + 1], x2 = cx[e + 2], x3 = cx[e + 3];
        const float4 r4 = wr4[q], z4 = wz4[q], n4 = wn4[q];
        axr = fma((double)r4.x, x0, axr); axr = fma((double)r4.y, x1, axr);
        axr = fma((double)r4.z, x2, axr); axr = fma((double)r4.w, x3, axr);
        axz = fma((double)z4.x, x0, axz); axz = fma((double)z4.y, x1, axz);
        axz = fma((double)z4.z, x2, axz); axz = fma((double)z4.w, x3, axz);
        axn = fma((double)n4.x, x0, axn); axn = fma((double)n4.y, x1, axn);
        axn = fma((double)n4.z, x2, axn); axn = fma((double)n4.w, x3, axn);
      }
      const float4* hr4 = reinterpret_cast<const float4*>(&wlds[wid * LD_NEUR + 2592]);
      const float4* hz4 = reinterpret_cast<const float4*>(&wlds[wid * LD_NEUR + 2592 + 800]);
      const float4* hn4 = reinterpret_cast<const float4*>(&wlds[wid * LD_NEUR + 2592 + 1600]);
      const double* sx = sOld + (size_t)b * H_;
      double ahr = 0., ahz = 0., ahn = 0.;
      for (int j = 0; j < 25; ++j) {
        const int q = ks + 8 * j;
        const int e = 4 * q;
        const double s0 = sx[e], s1 = sx[e + 1], s2 = sx[e + 2], s3 = sx[e + 3];
        const float4 r4 = hr4[q], z4 = hz4[q], n4 = hn4[q];
        ahr = fma((double)r4.x, s0, ahr); ahr = fma((double)r4.y, s1, ahr);
        ahr = fma((double)r4.z, s2, ahr); ahr = fma((double)r4.w, s3, ahr);
        ahz = fma((double)z4.x, s0, ahz); ahz = fma((double)z4.y, s1, ahz);
        ahz = fma((double)z4.z, s2, ahz); ahz = fma((double)z4.w, s3, ahz);
        ahn = fma((double)n4.x, s0, ahn); ahn = fma((double)n4.y, s1, ahn);
        ahn = fma((double)n4.z, s2, ahn); ahn = fma((double)n4.w, s3, ahn);
      }
      #pragma unroll
      for (int off = 1; off < 8; off <<= 1) {
        axr += __shfl_xor(axr, off); axz += __shfl_xor(axz, off); axn += __shfl_xor(axn, off);
        ahr += __shfl_xor(ahr, off); ahz += __shfl_xor(ahz, off); ahn += __shfl_xor(ahn, off);
      }
      if (ks == 0) {
        const double xr = axr + (double)b_ih[i], xz = axz + (double)b_ih[H_ + i],
                     xn = axn + (double)b_ih[2 * H_ + i];
        const double hr = ahr + (double)b_hh[i], hz = ahz + (double)b_hh[H_ + i],
                     hn = ahn + (double)b_hh[2 * H_ + i];
        const double r = 1.0 / (1.0 + exp(-(xr + hr)));
        const double z = 1.0 / (1.0 + exp(-(xz + hz)));
        const double n = tanh(xn + r * hn);
        const double sn = (1.0 - z) * n + z * sOld[b * H_ + i];
        sNew[b * H_ + i] = sn;
        res[((size_t)b * L_ + idx) * H_ + i] = (float)sn;
      }
    } else {
      int tsk = -1;
      if (bid >= 160) tsk = (bid - 160) * 8 + wid;          // 0..767
      else tsk = 768 + bid * 3 + (wid - 5);                  // 768..1247
      if (tsk < 1024 && idx > 0) {
        const int b = tsk >> 7, j = tsk & (L_ - 1);
        if (j < idx) {                           // guard: skip future rows
          const size_t bj = (size_t)b * L_ + j;
          double e0 = Gd[bj * A_ + lane], e1 = Gd[bj * A_ + lane + 64];
          const double an0 = angD[bj * 3], an1 = angD[bj * 3 + 1], an2 = angD[bj * 3 + 2];
          const double dd0 = dstR[bj * 3], dd1 = dstR[bj * 3 + 1], dd2 = dstR[bj * 3 + 2];
          e0 = fma((double)W1[864 * A_ + lane], an0, e0);
          e0 = fma((double)W1[865 * A_ + lane], an1, e0);
          e0 = fma((double)W1[866 * A_ + lane], an2, e0);
          e0 = fma((double)W1[867 * A_ + lane], dd0, e0);
          e0 = fma((double)W1[868 * A_ + lane], dd1, e0);
          e0 = fma((double)W1[869 * A_ + lane], dd2, e0);
          e1 = fma((double)W1[864 * A_ + lane + 64], an0, e1);
          e1 = fma((double)W1[865 * A_ + lane + 64], an1, e1);
          e1 = fma((double)W1[866 * A_ + lane + 64], an2, e1);
          e1 = fma((double)W1[867 * A_ + lane + 64], dd0, e1);
          e1 = fma((double)W1[868 * A_ + lane + 64], dd1, e1);
          e1 = fma((double)W1[869 * A_ + lane + 64], dd2, e1);
          e0 = tanh(e0); e1 = tanh(e1);
          double lg[8];
          #pragma unroll
          for (int h = 0; h < 8; ++h) {
            double v = fma(e0, (double)W2[lane * 8 + h], e1 * (double)W2[(lane + 64) * 8 + h]);
            #pragma unroll
            for (int off = 1; off < 64; off <<= 1) v += __shfl_xor(v, off);
            lg[h] = v;
          }
          if (lane == 0) {
            const bool valid = (dd1 <= RAD_);
            double* wrow = wAr + bj * HD_;
            #pragma unroll
            for (int h = 0; h < 8; ++h) wrow[h] = valid ? exp(lg[h]) : 0.0;
          }
        }
      }
    }
    gbarx(cnt, ep, xcc, xcnt, nx);

    // ---- P2: pooled (0..127) || G-update (128..135) || angle+pos+dist (136) ----
    if (bid < 128) {
      if (idx > 0) {
        const int b = bid >> 4, sl = bid & 15;
        const int f0 = sl * 55;
        const int fn = (F_ - f0 < 55) ? (F_ - f0) : 55;
        const int fl = tid >> 3, h = tid & 7;
        if (fl < fn) {
          const int f = f0 + fl;
          const float* fbf = nullptr; const double* fbd = nullptr; int strd = 0;
          if (f < H_)                { fbf = res  + f + (size_t)b * L_ * H_;               strd = H_;  }
          else if (f < H_ + IN_)     { fbf = data + (f - H_) + (size_t)b * L_ * IN_;       strd = IN_; }
          else if (f < H_ + IN_ + 3) { fbd = angD + (f - H_ - IN_) + (size_t)b * L_ * 3;   strd = 3;   }
          else                       { fbd = dstR + (f - H_ - IN_ - 3) + (size_t)b * L_ * 3; strd = 3; }
          const double* wp = wAr + (size_t)b * L_ * HD_ + h;
          double acc = 0.0, zs = 0.0;
          for (int j = 0; j < idx; ++j) {
            const double wj = wp[(size_t)j * HD_];
            zs += wj;
            const double fv = fbf ? (double)fbf[(size_t)j * strd] : fbd[(size_t)j * strd];
            acc = fma(wj, fv, acc);
          }
          pND[(size_t)b * KO_ + (size_t)h * F_ + f] = acc / zs;
        }
      }
    } else if (bid < 136) {
      const int b = bid - 128;                   // G-row update for step idx
      const int a = tid & (A_ - 1), ksl = tid >> 7;
      const double* sr = sNew + (size_t)b * H_;
      const int i0 = ksl * 200;
      double p = 0.0;
      for (int k = 0; k < 200; ++k)
        p = fma(sr[i0 + k], (double)W1[(size_t)(i0 + k) * A_ + a], p);
      smd[tid] = p;
      __syncthreads();
      if (tid < 128)
        Gd[((size_t)b * L_ + idx) * A_ + tid] +=
            smd[tid] + smd[128 + tid] + smd[256 + tid] + smd[384 + tid];
    } else if (bid == 136) {
      const int b7 = tid / 48, rem = tid % 48, t3 = rem / 16, ksl = rem & 15;
      if (tid < 384) {
        const double* sr = sNew + (size_t)b7 * H_;
        const int i0 = ksl * 50;
        double p = 0.0;
        for (int k = 0; k < 50; ++k)
          p = fma(sr[i0 + k], (double)Wa[(i0 + k) * 3 + t3], p);
        smd[tid] = p;
      }
      __syncthreads();
      if (tid < 24) {
        const int b2 = tid / 3, t4 = tid % 3;
        double s = (double)ba[t4];
        for (int u = 0; u < 16; ++u) s += smd[b2 * 48 + t4 * 16 + u];
        smd[384 + tid] = s;
        angD[((size_t)b2 * L_ + idx) * 3 + t4] = s;
        out[(size_t)B_ * L_ * 9 + ((size_t)b2 * L_ + idx) * 3 + t4] = (float)s;
      }
      __syncthreads();
      if (tid < 24) {
        const int b2 = tid / 3, t4 = tid % 3;
        const double a = smd[384 + b2 * 3 + t4];
        const double asum = smd[384 + b2 * 3] + smd[384 + b2 * 3 + 1] + smd[384 + b2 * 3 + 2];
        const double sa = sin(a), ca = cos(a), cs = cos(asum), ss = sin(asum);
        double px = 0., py = 0., pz = 0.;
        if (idx > 0) {
          const double* pr = posD + ((size_t)b2 * L_ + idx - 1) * 9 + t4 * 3;
          px = pr[0]; py = pr[1]; pz = pr[2];
        }
        px = fma(BOND_, ca, px);
        py = fma(BOND_, sa * cs, py);
        pz = fma(BOND_, sa * ss, pz);
        double* pw = posD + ((size_t)b2 * L_ + idx) * 9 + t4 * 3;
        pw[0] = px; pw[1] = py; pw[2] = pz;
        float* ow = out + ((size_t)b2 * L_ + idx) * 9 + t4 * 3;
        ow[0] = (float)px; ow[1] = (float)py; ow[2] = (float)pz;
      }
      __syncthreads();
      if (idx < L_ - 1) {                        // dist rows j<=idx vs pos[idx]
        for (int u = tid; u < 4096; u += NT) {
          const int b = u >> 9, rem2 = u & 511;
          const int j = rem2 >> 2, t6 = rem2 & 3;
          if (t6 < 3 && j <= idx) {
            const double* pa = posD + ((size_t)b * L_ + idx) * 9 + t6 * 3;
            const double* pb = posD + ((size_t)b * L_ + j) * 9 + t6 * 3;
            const double dx = pa[0] - pb[0], dy = pa[1] - pb[1], dz = pa[2] - pb[2];
            dstW[((size_t)b * L_ + j) * 3 + t6] =
                sqrt(fma(dx, dx, fma(dy, dy, fma(dz, dz, 1e-12))));
          }
        }
      }
    }
    gbarx(cnt, ep, xcc, xcnt, nx);

    // ---- P3: ctx = pooledN @ Wout(LDS cols) + bout ----
    if (idx < L_ - 1) {
      const int ntask = (bid < 160) ? 2 : 5;
      for (int u = 0; u < ntask; ++u) {
        const int t = wid + 8 * u;
        const int cs = t >> 3, b = t & 7;
        const int c = (bid < 160) ? (bid * 2 + cs) : (320 + (bid - 160) * 5 + cs);
        const int cbase = ((bid < 160) ? LD_WOUT_A : 0) + cs * KO_;
        double acc = 0.0;
        if (idx > 0) {
          const double* pr = pND + (size_t)b * KO_;
          for (int m = 0; m < 28; ++m) {
            const int q = lane + 64 * m;
            if (q < 1740) {
              const float4 w4 = *reinterpret_cast<const float4*>(&wlds[cbase + 4 * q]);
              const int e = 4 * q;
              acc = fma((double)w4.x, pr[e],     acc);
              acc = fma((double)w4.y, pr[e + 1], acc);
              acc = fma((double)w4.z, pr[e + 2], acc);
              acc = fma((double)w4.w, pr[e + 3], acc);
            }
          }
          #pragma unroll
          for (int off = 1; off < 64; off <<= 1) acc += __shfl_xor(acc, off);
        }
        if (lane == 0)
          ctxD[b * C_ + c] = (idx > 0) ? (acc + (double)bout[c]) : 0.0;
      }
    }
    gbarx(cnt, ep, xcc, xcnt, nx);
  }
}

extern "C" void kernel_launch(void* const* d_in, const int* in_sizes, int n_in,
                              void* d_out, int out_size, void* d_ws, size_t ws_size,
                              hipStream_t stream) {
  (void)in_sizes; (void)n_in; (void)out_size;
  if (ws_size < WS_BYTES) return;
  const float* data = (const float*)d_in[0];
  const float* W_ih = (const float*)d_in[1];
  const float* W_hh = (const float*)d_in[2];
  const float* b_ih = (const float*)d_in[3];
  const float* b_hh = (const float*)d_in[4];
  const float* Wa   = (const float*)d_in[5];
  const float* ba   = (const float*)d_in[6];
  const float* W1   = (const float*)d_in[7];
  const float* b1   = (const float*)d_in[8];
  const float* W2   = (const float*)d_in[9];
  const float* Wout = (const float*)d_in[10];
  const float* bout = (const float*)d_in[11];
  hipMemsetAsync(d_ws, 0, 8192, stream);         // reset barrier state (replay-safe)
  srnn<<<dim3(NB), dim3(NT), 0, stream>>>(data, W_ih, W_hh, b_ih, b_hh, Wa, ba,
                                          W1, b1, W2, Wout, bout,
                                          (float*)d_out, (float*)d_ws);
}

// Round 11
// 10754.214 us; speedup vs baseline: 1.6281x; 1.0583x over previous
//
#include <hip/hip_runtime.h>
#include <cmath>

namespace {

constexpr int B_ = 8, L_ = 128, IN_ = 64, H_ = 800, C_ = 800, A_ = 128, HD_ = 8;
constexpr int F_ = 870;
constexpr int KX_ = IN_ + C_;          // 864
constexpr int KO_ = HD_ * F_;          // 6960
constexpr double RAD_ = 8.0, BOND_ = 3.8;
constexpr int NB = 256, NT = 512;

// ---- barrier state: first 8 KB of ws, 128B-line granular ----
// line 0-7  : main arrival counter per XCD   cnt[x*32]
// line 8-15 : per-XCD ready flags            cnt[(8+x)*32]
// line 16   : global done counter            cnt[512]
// line 17-24: per-XCD block census           cnt[(17+x)*32]
// line 25-32: init-barrier arrivals          cnt[(25+g)*32]
// line 33-40: init-barrier release flags     cnt[(33+g)*32]
constexpr size_t OF_RES = 2048;                                 // res [B][L][H] f32
constexpr size_t OF_WIT = OF_RES + (size_t)B_ * L_ * H_;        // W_ih^T [2400][864]
constexpr size_t OF_WHT = OF_WIT + (size_t)3 * H_ * KX_;        // W_hh^T [2400][800]
constexpr size_t OF_WOT = OF_WHT + (size_t)3 * H_ * H_;         // Wout^T [800][6960]
constexpr size_t FLT_END = OF_WOT + (size_t)C_ * KO_;           // even
// ---- double region ----
constexpr size_t D_ST  = 0;                                     // state dbuf [2][B][H]
constexpr size_t D_CTX = D_ST + 2ull * B_ * H_;                 // context [B][C]
constexpr size_t D_ANG = D_CTX + (size_t)B_ * C_;               // angles [B][L][3]
constexpr size_t D_POS = D_ANG + (size_t)B_ * L_ * 3;           // positions [B][L][3][3]
constexpr size_t D_DST = D_POS + (size_t)B_ * L_ * 9;           // dist [2][B][L][3] parity
constexpr size_t D_G   = D_DST + 2ull * B_ * L_ * 3;            // G [B][L][A]
constexpr size_t D_W   = D_G + (size_t)B_ * L_ * A_;            // w [B][L][HD]
constexpr size_t D_PN  = D_W + (size_t)B_ * L_ * HD_;           // pooledN [B][KO]
constexpr size_t D_END = D_PN + (size_t)B_ * KO_;
constexpr size_t WS_BYTES = FLT_END * 4 + D_END * 8;            // ~43.4 MB

// LDS geometry (floats). Type-A (bid<160): 5 neurons + 2 Wout cols.
// Type-B (bid>=160): 5 Wout cols.
constexpr int LD_NEUR = 4992;          // per-neuron: 3*864 ih + 3*800 hh
constexpr int LD_WOUT_A = 24960;       // type-A Wout base (5*4992)
constexpr int LD_TOT = 38880;          // 155,520 B

// One-time init barrier (r6/r10-proven: release adds + per-block acquire).
__device__ __forceinline__ void gbar_init(unsigned* cnt) {
  __syncthreads();
  const unsigned grp = (unsigned)blockIdx.x >> 5;
  if (threadIdx.x == 0)
    __hip_atomic_fetch_add(&cnt[(25 + grp) * 32], 1u,
                           __ATOMIC_RELEASE, __HIP_MEMORY_SCOPE_AGENT);
  if (blockIdx.x == 0) {
    if (threadIdx.x < 8) {
      while (__hip_atomic_load(&cnt[(25 + threadIdx.x) * 32],
                               __ATOMIC_RELAXED, __HIP_MEMORY_SCOPE_AGENT) < 32u)
        __builtin_amdgcn_s_sleep(8);
    }
    if (threadIdx.x == 0)
      __builtin_amdgcn_fence(__ATOMIC_ACQUIRE, "agent");
    __syncthreads();
    if (threadIdx.x < 8)
      __hip_atomic_store(&cnt[(33 + threadIdx.x) * 32], 1u,
                         __ATOMIC_RELEASE, __HIP_MEMORY_SCOPE_AGENT);
    __syncthreads();
  } else {
    if (threadIdx.x == 0) {
      while (__hip_atomic_load(&cnt[(33 + grp) * 32],
                               __ATOMIC_RELAXED, __HIP_MEMORY_SCOPE_AGENT) < 1u)
        __builtin_amdgcn_s_sleep(8);
      __builtin_amdgcn_fence(__ATOMIC_ACQUIRE, "agent");
    }
    __syncthreads();
  }
}

// Main-loop barrier: ONE wbl2 per XCD (r10) and now ONE L2-inv per XCD.
// The elected last-arriver per XCD: release-fence (wbl2) -> done-add ->
// poll global done -> acquire-fence (L2 inv, covers the whole XCD) ->
// raise per-XCD ready flag. Peers poll the flag (LLC atomics bypass the
// caches), then flash-invalidate ONLY their CU's L1 (buffer_inv sc0 =
// SE-scope) -- the stale-L1 hazard is per-CU, the stale-L2 hazard was
// handled once by the master. L2-inv count/barrier: 256 -> 8.
__device__ __forceinline__ void gbarx(unsigned* cnt, unsigned& ep,
                                      unsigned xcc, unsigned xcnt, unsigned nx) {
  ++ep;
  __syncthreads();                               // drains all waves' vmcnt
  if (threadIdx.x == 0) {
    const unsigned old = __hip_atomic_fetch_add(&cnt[xcc * 32], 1u,
                             __ATOMIC_RELAXED, __HIP_MEMORY_SCOPE_AGENT);
    if (old == ep * xcnt - 1u) {                 // last arriver on this XCD
      __builtin_amdgcn_fence(__ATOMIC_RELEASE, "agent");   // ONE wbl2 / XCD
      __hip_atomic_fetch_add(&cnt[512], 1u,
                             __ATOMIC_RELAXED, __HIP_MEMORY_SCOPE_AGENT);
      while (__hip_atomic_load(&cnt[512],
                               __ATOMIC_RELAXED, __HIP_MEMORY_SCOPE_AGENT) < ep * nx)
        __builtin_amdgcn_s_sleep(2);
      __builtin_amdgcn_fence(__ATOMIC_ACQUIRE, "agent");   // ONE L2-inv / XCD
      __hip_atomic_store(&cnt[(8 + xcc) * 32], ep,
                         __ATOMIC_RELAXED, __HIP_MEMORY_SCOPE_AGENT);
    } else {
      while (__hip_atomic_load(&cnt[(8 + xcc) * 32],
                               __ATOMIC_RELAXED, __HIP_MEMORY_SCOPE_AGENT) < ep)
        __builtin_amdgcn_s_sleep(2);
      // master already inv'd this XCD's L2; flash our CU's L1 only
      asm volatile("buffer_inv sc0\n\ts_waitcnt vmcnt(0)" ::: "memory");
    }
  }
  __syncthreads();
}

__device__ void transp(const float* __restrict__ src, float* __restrict__ dst,
                       int R, int Cn, float* sm) {
  const int tr_ = (R + 31) >> 5, tc_ = (Cn + 31) >> 5;
  for (int t = blockIdx.x; t < tr_ * tc_; t += gridDim.x) {
    const int r0 = (t / tc_) << 5, c0 = (t % tc_) << 5;
    __syncthreads();
    for (int e = threadIdx.x; e < 1024; e += NT) {
      const int rr = e >> 5, cc = e & 31, r = r0 + rr, c = c0 + cc;
      sm[rr * 33 + cc] = (r < R && c < Cn) ? src[(size_t)r * Cn + c] : 0.0f;
    }
    __syncthreads();
    for (int e = threadIdx.x; e < 1024; e += NT) {
      const int cc = e >> 5, rr = e & 31, r = r0 + rr, c = c0 + cc;
      if (r < R && c < Cn) dst[(size_t)c * R + r] = sm[rr * 33 + cc];
    }
  }
}

} // namespace

extern "C" __global__ __launch_bounds__(NT, 1)
void srnn(const float* __restrict__ data, const float* __restrict__ W_ih,
          const float* __restrict__ W_hh, const float* __restrict__ b_ih,
          const float* __restrict__ b_hh, const float* __restrict__ Wa,
          const float* __restrict__ ba, const float* __restrict__ W1,
          const float* __restrict__ b1, const float* __restrict__ W2,
          const float* __restrict__ Wout, const float* __restrict__ bout,
          float* __restrict__ out, float* __restrict__ ws)
{
  __shared__ __align__(16) float wlds[LD_TOT];   // 155,520 B persistent weights
  __shared__ double smd[528];                    // 4,224 B scratch (1056 floats)
  __shared__ unsigned s_xcc, s_xcnt, s_nx;
  float* smf = (float*)smd;
  unsigned* cnt = (unsigned*)ws;
  float* res   = ws + OF_RES;
  float* WihT  = ws + OF_WIT;
  float* WhhT  = ws + OF_WHT;
  float* WoutT = ws + OF_WOT;
  double* wd   = (double*)(ws + FLT_END);
  double* st2  = wd + D_ST;
  double* ctxD = wd + D_CTX;
  double* angD = wd + D_ANG;
  double* posD = wd + D_POS;
  double* dstD = wd + D_DST;                     // [2][B][L][3]
  double* Gd   = wd + D_G;
  double* wAr  = wd + D_W;
  double* pND  = wd + D_PN;

  const int bid = blockIdx.x, tid = threadIdx.x;
  const int wid = tid >> 6, lane = tid & 63;
  unsigned ep = 0;

  // ---- XCD discovery (m09: HW_REG_XCC_ID verified on gfx950) ----
  if (tid == 0) {
    unsigned x;
    asm volatile("s_getreg_b32 %0, hwreg(HW_REG_XCC_ID)" : "=s"(x));
    x &= 7u;
    s_xcc = x;
    __hip_atomic_fetch_add(&cnt[(17 + x) * 32], 1u,
                           __ATOMIC_RELAXED, __HIP_MEMORY_SCOPE_AGENT);
  }

  // ================= init (covered by fenced gbar_init) =================
  for (int i = bid * NT + tid; i < (int)(D_ANG - D_ST); i += NB * NT)
    wd[i] = 0.0;                                 // state dbuf + ctx = 0
  {
    const int i = bid * NT + tid;                // B*L*A == NB*NT
    const int a = i & (A_ - 1);
    const int bj = i >> 7;
    double acc = (double)b1[a];
    const float* dr = data + (size_t)bj * IN_;
    #pragma unroll 8
    for (int k = 0; k < IN_; ++k)
      acc = fma((double)dr[k], (double)W1[(size_t)(H_ + k) * A_ + a], acc);
    Gd[i] = acc;
  }
  transp(W_ih, WihT, KX_, 3 * H_, smf);          // coalesced staging (r4-proven)
  transp(W_hh, WhhT, H_, 3 * H_, smf);
  transp(Wout, WoutT, KO_, C_, smf);
  gbar_init(cnt);

  // ---- read back XCD census (stable after init barrier) ----
  if (tid == 0) {
    unsigned n = 0;
    for (int k = 0; k < 8; ++k)
      n += (__hip_atomic_load(&cnt[(17 + k) * 32],
                              __ATOMIC_RELAXED, __HIP_MEMORY_SCOPE_AGENT) > 0u);
    s_nx = n;
    s_xcnt = __hip_atomic_load(&cnt[(17 + s_xcc) * 32],
                               __ATOMIC_RELAXED, __HIP_MEMORY_SCOPE_AGENT);
  }

  // ---- persistent LDS weight slices (coalesced float4 from transposed) ----
  if (bid < 160) {
    for (int rg = 0; rg < 15; ++rg) {            // ih rows: 5 neurons x 3 gates
      const int s = rg / 3, g = rg % 3;
      const int i = bid * 5 + s;
      const float4* src = reinterpret_cast<const float4*>(WihT + (size_t)(g * H_ + i) * KX_);
      float4* dst = reinterpret_cast<float4*>(&wlds[s * LD_NEUR + g * 864]);
      for (int k4 = tid; k4 < 216; k4 += NT) dst[k4] = src[k4];
    }
    for (int rg = 0; rg < 15; ++rg) {            // hh rows
      const int s = rg / 3, g = rg % 3;
      const int i = bid * 5 + s;
      const float4* src = reinterpret_cast<const float4*>(WhhT + (size_t)(g * H_ + i) * H_);
      float4* dst = reinterpret_cast<float4*>(&wlds[s * LD_NEUR + 2592 + g * 800]);
      for (int k4 = tid; k4 < 200; k4 += NT) dst[k4] = src[k4];
    }
    for (int cs = 0; cs < 2; ++cs) {             // 2 Wout cols
      const int c = bid * 2 + cs;
      const float4* src = reinterpret_cast<const float4*>(WoutT + (size_t)c * KO_);
      float4* dst = reinterpret_cast<float4*>(&wlds[LD_WOUT_A + cs * KO_]);
      for (int k4 = tid; k4 < 1740; k4 += NT) dst[k4] = src[k4];
    }
  } else {
    for (int cs = 0; cs < 5; ++cs) {             // 5 Wout cols
      const int c = 320 + (bid - 160) * 5 + cs;
      const float4* src = reinterpret_cast<const float4*>(WoutT + (size_t)c * KO_);
      float4* dst = reinterpret_cast<float4*>(&wlds[cs * KO_]);
      for (int k4 = tid; k4 < 1740; k4 += NT) dst[k4] = src[k4];
    }
  }
  __syncthreads();
  const unsigned xcc = s_xcc, xcnt = s_xcnt, nx = s_nx;

  // ================= 128 steps, 3 barriers each =================
  for (int idx = 0; idx < L_; ++idx) {
    const int rp = idx & 1;
    const double* sOld = st2 + (size_t)rp * B_ * H_;
    double* sNew = st2 + (size_t)(rp ^ 1) * B_ * H_;
    const double* dstR = dstD + (size_t)(idx & 1) * (B_ * L_ * 3);       // read
    double* dstW = dstD + (size_t)((idx + 1) & 1) * (B_ * L_ * 3);       // write

    // ---- P1: GRU (type-A waves 0..4) || e/logits/w (1024 waves) ----
    if (bid < 160 && wid < 5) {
      const int i = bid * 5 + wid;               // neuron
      const int b = lane >> 3, ks = lane & 7;
      const float4* wr4 = reinterpret_cast<const float4*>(&wlds[wid * LD_NEUR]);
      const float4* wz4 = reinterpret_cast<const float4*>(&wlds[wid * LD_NEUR + 864]);
      const float4* wn4 = reinterpret_cast<const float4*>(&wlds[wid * LD_NEUR + 1728]);
      const float4* dx4 = reinterpret_cast<const float4*>(data + ((size_t)b * L_ + idx) * IN_);
      const double* cx = ctxD + (size_t)b * C_;
      double axr = 0., axz = 0., axn = 0.;
      #pragma unroll
      for (int j = 0; j < 2; ++j) {
        const int q = ks + 8 * j;
        const float4 x4 = dx4[q];
        const float4 r4 = wr4[q], z4 = wz4[q], n4 = wn4[q];
        const double x0 = x4.x, x1 = x4.y, x2 = x4.z, x3 = x4.w;
        axr = fma((double)r4.x, x0, axr); axr = fma((double)r4.y, x1, axr);
        axr = fma((double)r4.z, x2, axr); axr = fma((double)r4.w, x3, axr);
        axz = fma((double)z4.x, x0, axz); axz = fma((double)z4.y, x1, axz);
        axz = fma((double)z4.z, x2, axz); axz = fma((double)z4.w, x3, axz);
        axn = fma((double)n4.x, x0, axn); axn = fma((double)n4.y, x1, axn);
        axn = fma((double)n4.z, x2, axn); axn = fma((double)n4.w, x3, axn);
      }
      for (int j = 2; j < 27; ++j) {
        const int q = ks + 8 * j;
        const int e = 4 * q - 64;
        const double x0 = cx[e], x1 = cx[e + 1], x2 = cx[e + 2], x3 = cx[e + 3];
        const float4 r4 = wr4[q], z4 = wz4[q], n4 = wn4[q];
        axr = fma((double)r4.x, x0, axr); axr = fma((double)r4.y, x1, axr);
        axr = fma((double)r4.z, x2, axr); axr = fma((double)r4.w, x3, axr);
        axz = fma((double)z4.x, x0, axz); axz = fma((double)z4.y, x1, axz);
        axz = fma((double)z4.z, x2, axz); axz = fma((double)z4.w, x3, axz);
        axn = fma((double)n4.x, x0, axn); axn = fma((double)n4.y, x1, axn);
        axn = fma((double)n4.z, x2, axn); axn = fma((double)n4.w, x3, axn);
      }
      const float4* hr4 = reinterpret_cast<const float4*>(&wlds[wid * LD_NEUR + 2592]);
      const float4* hz4 = reinterpret_cast<const float4*>(&wlds[wid * LD_NEUR + 2592 + 800]);
      const float4* hn4 = reinterpret_cast<const float4*>(&wlds[wid * LD_NEUR + 2592 + 1600]);
      const double* sx = sOld + (size_t)b * H_;
      double ahr = 0., ahz = 0., ahn = 0.;
      for (int j = 0; j < 25; ++j) {
        const int q = ks + 8 * j;
        const int e = 4 * q;
        const double s0 = sx[e], s1 = sx[e + 1], s2 = sx[e + 2], s3 = sx[e + 3];
        const float4 r4 = hr4[q], z4 = hz4[q], n4 = hn4[q];
        ahr = fma((double)r4.x, s0, ahr); ahr = fma((double)r4.y, s1, ahr);
        ahr = fma((double)r4.z, s2, ahr); ahr = fma((double)r4.w, s3, ahr);
        ahz = fma((double)z4.x, s0, ahz); ahz = fma((double)z4.y, s1, ahz);
        ahz = fma((double)z4.z, s2, ahz); ahz = fma((double)z4.w, s3, ahz);
        ahn = fma((double)n4.x, s0, ahn); ahn = fma((double)n4.y, s1, ahn);
        ahn = fma((double)n4.z, s2, ahn); ahn = fma((double)n4.w, s3, ahn);
      }
      #pragma unroll
      for (int off = 1; off < 8; off <<= 1) {
        axr += __shfl_xor(axr, off); axz += __shfl_xor(axz, off); axn += __shfl_xor(axn, off);
        ahr += __shfl_xor(ahr, off); ahz += __shfl_xor(ahz, off); ahn += __shfl_xor(ahn, off);
      }
      if (ks == 0) {
        const double xr = axr + (double)b_ih[i], xz = axz + (double)b_ih[H_ + i],
                     xn = axn + (double)b_ih[2 * H_ + i];
        const double hr = ahr + (double)b_hh[i], hz = ahz + (double)b_hh[H_ + i],
                     hn = ahn + (double)b_hh[2 * H_ + i];
        const double r = 1.0 / (1.0 + exp(-(xr + hr)));
        const double z = 1.0 / (1.0 + exp(-(xz + hz)));
        const double n = tanh(xn + r * hn);
        const double sn = (1.0 - z) * n + z * sOld[b * H_ + i];
        sNew[b * H_ + i] = sn;
        res[((size_t)b * L_ + idx) * H_ + i] = (float)sn;
      }
    } else {
      int tsk = -1;
      if (bid >= 160) tsk = (bid - 160) * 8 + wid;          // 0..767
      else tsk = 768 + bid * 3 + (wid - 5);                  // 768..1247
      if (tsk < 1024 && idx > 0) {
        const int b = tsk >> 7, j = tsk & (L_ - 1);
        if (j < idx) {                           // guard: skip future rows
          const size_t bj = (size_t)b * L_ + j;
          double e0 = Gd[bj * A_ + lane], e1 = Gd[bj * A_ + lane + 64];
          const double an0 = angD[bj * 3], an1 = angD[bj * 3 + 1], an2 = angD[bj * 3 + 2];
          const double dd0 = dstR[bj * 3], dd1 = dstR[bj * 3 + 1], dd2 = dstR[bj * 3 + 2];
          e0 = fma((double)W1[864 * A_ + lane], an0, e0);
          e0 = fma((double)W1[865 * A_ + lane], an1, e0);
          e0 = fma((double)W1[866 * A_ + lane], an2, e0);
          e0 = fma((double)W1[867 * A_ + lane], dd0, e0);
          e0 = fma((double)W1[868 * A_ + lane], dd1, e0);
          e0 = fma((double)W1[869 * A_ + lane], dd2, e0);
          e1 = fma((double)W1[864 * A_ + lane + 64], an0, e1);
          e1 = fma((double)W1[865 * A_ + lane + 64], an1, e1);
          e1 = fma((double)W1[866 * A_ + lane + 64], an2, e1);
          e1 = fma((double)W1[867 * A_ + lane + 64], dd0, e1);
          e1 = fma((double)W1[868 * A_ + lane + 64], dd1, e1);
          e1 = fma((double)W1[869 * A_ + lane + 64], dd2, e1);
          e0 = tanh(e0); e1 = tanh(e1);
          double lg[8];
          #pragma unroll
          for (int h = 0; h < 8; ++h) {
            double v = fma(e0, (double)W2[lane * 8 + h], e1 * (double)W2[(lane + 64) * 8 + h]);
            #pragma unroll
            for (int off = 1; off < 64; off <<= 1) v += __shfl_xor(v, off);
            lg[h] = v;
          }
          if (lane == 0) {
            const bool valid = (dd1 <= RAD_);
            double* wrow = wAr + bj * HD_;
            #pragma unroll
            for (int h = 0; h < 8; ++h) wrow[h] = valid ? exp(lg[h]) : 0.0;
          }
        }
      }
    }
    gbarx(cnt, ep, xcc, xcnt, nx);

    // ---- P2: pooled (0..127) || G-update (128..135) || angle+pos+dist (136) ----
    if (bid < 128) {
      if (idx > 0) {
        const int b = bid >> 4, sl = bid & 15;
        const int f0 = sl * 55;
        const int fn = (F_ - f0 < 55) ? (F_ - f0) : 55;
        const int fl = tid >> 3, h = tid & 7;
        if (fl < fn) {
          const int f = f0 + fl;
          const float* fbf = nullptr; const double* fbd = nullptr; int strd = 0;
          if (f < H_)                { fbf = res  + f + (size_t)b * L_ * H_;               strd = H_;  }
          else if (f < H_ + IN_)     { fbf = data + (f - H_) + (size_t)b * L_ * IN_;       strd = IN_; }
          else if (f < H_ + IN_ + 3) { fbd = angD + (f - H_ - IN_) + (size_t)b * L_ * 3;   strd = 3;   }
          else                       { fbd = dstR + (f - H_ - IN_ - 3) + (size_t)b * L_ * 3; strd = 3; }
          const double* wp = wAr + (size_t)b * L_ * HD_ + h;
          double acc = 0.0, zs = 0.0;
          for (int j = 0; j < idx; ++j) {
            const double wj = wp[(size_t)j * HD_];
            zs += wj;
            const double fv = fbf ? (double)fbf[(size_t)j * strd] : fbd[(size_t)j * strd];
            acc = fma(wj, fv, acc);
          }
          pND[(size_t)b * KO_ + (size_t)h * F_ + f] = acc / zs;
        }
      }
    } else if (bid < 136) {
      const int b = bid - 128;                   // G-row update for step idx
      const int a = tid & (A_ - 1), ksl = tid >> 7;
      const double* sr = sNew + (size_t)b * H_;
      const int i0 = ksl * 200;
      double p = 0.0;
      for (int k = 0; k < 200; ++k)
        p = fma(sr[i0 + k], (double)W1[(size_t)(i0 + k) * A_ + a], p);
      smd[tid] = p;
      __syncthreads();
      if (tid < 128)
        Gd[((size_t)b * L_ + idx) * A_ + tid] +=
            smd[tid] + smd[128 + tid] + smd[256 + tid] + smd[384 + tid];
    } else if (bid == 136) {
      const int b7 = tid / 48, rem = tid % 48, t3 = rem / 16, ksl = rem & 15;
      if (tid < 384) {
        const double* sr = sNew + (size_t)b7 * H_;
        const int i0 = ksl * 50;
        double p = 0.0;
        for (int k = 0; k < 50; ++k)
          p = fma(sr[i0 + k], (double)Wa[(i0 + k) * 3 + t3], p);
        smd[tid] = p;
      }
      __syncthreads();
      if (tid < 24) {
        const int b2 = tid / 3, t4 = tid % 3;
        double s = (double)ba[t4];
        for (int u = 0; u < 16; ++u) s += smd[b2 * 48 + t4 * 16 + u];
        smd[384 + tid] = s;
        angD[((size_t)b2 * L_ + idx) * 3 + t4] = s;
        out[(size_t)B_ * L_ * 9 + ((size_t)b2 * L_ + idx) * 3 + t4] = (float)s;
      }
      __syncthreads();
      if (tid < 24) {
        const int b2 = tid / 3, t4 = tid % 3;
        const double a = smd[384 + b2 * 3 + t4];
        const double asum = smd[384 + b2 * 3] + smd[384 + b2 * 3 + 1] + smd[384 + b2 * 3 + 2];
        const double sa = sin(a), ca = cos(a), cs = cos(asum), ss = sin(asum);
        double px = 0., py = 0., pz = 0.;
        if (idx > 0) {
          const double* pr = posD + ((size_t)b2 * L_ + idx - 1) * 9 + t4 * 3;
          px = pr[0]; py = pr[1]; pz = pr[2];
        }
        px = fma(BOND_, ca, px);
        py = fma(BOND_, sa * cs, py);
        pz = fma(BOND_, sa * ss, pz);
        double* pw = posD + ((size_t)b2 * L_ + idx) * 9 + t4 * 3;
        pw[0] = px; pw[1] = py; pw[2] = pz;
        float* ow = out + ((size_t)b2 * L_ + idx) * 9 + t4 * 3;
        ow[0] = (float)px; ow[1] = (float)py; ow[2] = (float)pz;
      }
      __syncthreads();
      if (idx < L_ - 1) {                        // dist rows j<=idx vs pos[idx]
        for (int u = tid; u < 4096; u += NT) {
          const int b = u >> 9, rem2 = u & 511;
          const int j = rem2 >> 2, t6 = rem2 & 3;
          if (t6 < 3 && j <= idx) {
            const double* pa = posD + ((size_t)b * L_ + idx) * 9 + t6 * 3;
            const double* pb = posD + ((size_t)b * L_ + j) * 9 + t6 * 3;
            const double dx = pa[0] - pb[0], dy = pa[1] - pb[1], dz = pa[2] - pb[2];
            dstW[((size_t)b * L_ + j) * 3 + t6] =
                sqrt(fma(dx, dx, fma(dy, dy, fma(dz, dz, 1e-12))));
          }
        }
      }
    }
    gbarx(cnt, ep, xcc, xcnt, nx);

    // ---- P3: ctx = pooledN @ Wout(LDS cols) + bout ----
    if (idx < L_ - 1) {
      const int ntask = (bid < 160) ? 2 : 5;
      for (int u = 0; u < ntask; ++u) {
        const int t = wid + 8 * u;
        const int cs = t >> 3, b = t & 7;
        const int c = (bid < 160) ? (bid * 2 + cs) : (320 + (bid - 160) * 5 + cs);
        const int cbase = ((bid < 160) ? LD_WOUT_A : 0) + cs * KO_;
        double acc = 0.0;
        if (idx > 0) {
          const double* pr = pND + (size_t)b * KO_;
          for (int m = 0; m < 28; ++m) {
            const int q = lane + 64 * m;
            if (q < 1740) {
              const float4 w4 = *reinterpret_cast<const float4*>(&wlds[cbase + 4 * q]);
              const int e = 4 * q;
              acc = fma((double)w4.x, pr[e],     acc);
              acc = fma((double)w4.y, pr[e + 1], acc);
              acc = fma((double)w4.z, pr[e + 2], acc);
              acc = fma((double)w4.w, pr[e + 3], acc);
            }
          }
          #pragma unroll
          for (int off = 1; off < 64; off <<= 1) acc += __shfl_xor(acc, off);
        }
        if (lane == 0)
          ctxD[b * C_ + c] = (idx > 0) ? (acc + (double)bout[c]) : 0.0;
      }
    }
    gbarx(cnt, ep, xcc, xcnt, nx);
  }
}

extern "C" void kernel_launch(void* const* d_in, const int* in_sizes, int n_in,
                              void* d_out, int out_size, void* d_ws, size_t ws_size,
                              hipStream_t stream) {
  (void)in_sizes; (void)n_in; (void)out_size;
  if (ws_size < WS_BYTES) return;
  const float* data = (const float*)d_in[0];
  const float* W_ih = (const float*)d_in[1];
  const float* W_hh = (const float*)d_in[2];
  const float* b_ih = (const float*)d_in[3];
  const float* b_hh = (const float*)d_in[4];
  const float* Wa   = (const float*)d_in[5];
  const float* ba   = (const float*)d_in[6];
  const float* W1   = (const float*)d_in[7];
  const float* b1   = (const float*)d_in[8];
  const float* W2   = (const float*)d_in[9];
  const float* Wout = (const float*)d_in[10];
  const float* bout = (const float*)d_in[11];
  hipMemsetAsync(d_ws, 0, 8192, stream);         // reset barrier state (replay-safe)
  srnn<<<dim3(NB), dim3(NT), 0, stream>>>(data, W_ih, W_hh, b_ih, b_hh, Wa, ba,
                                          W1, b1, W2, Wout, bout,
                                          (float*)d_out, (float*)d_ws);
}